// Round 5
// baseline (813.108 us; speedup 1.0000x reference)
//
#include <hip/hip_runtime.h>
#include <hip/hip_bf16.h>
#include <math.h>

typedef __hip_bfloat16 bf16;
using v8bf = __attribute__((ext_vector_type(8))) __bf16;
using v4f  = __attribute__((ext_vector_type(4))) float;
using f32x16 = __attribute__((ext_vector_type(16))) float;
using v4u = __attribute__((ext_vector_type(4))) unsigned;
using v4s = __attribute__((ext_vector_type(4))) short;
using v8s = __attribute__((ext_vector_type(8))) short;

#define T_SEQ 2048
#define DMODEL 2048
#define NHEADS 16
#define HDIM 128
#define RDIM 64

__device__ __forceinline__ short f2bfbits(float f) {
  bf16 h = __float2bfloat16(f);
  short s;
  __builtin_memcpy(&s, &h, 2);
  return s;
}

__device__ __forceinline__ unsigned pk2bf(float a, float b) {
  unsigned lo = (unsigned short)f2bfbits(a);
  unsigned hi = (unsigned short)f2bfbits(b);
  return lo | (hi << 16);
}

// async global->LDS, 16B per lane (GEMM staging only)
typedef const __attribute__((address_space(1))) unsigned gu32;
typedef __attribute__((address_space(3))) unsigned lu32;
__device__ __forceinline__ void gl_lds16(const void* g, void* l) {
  __builtin_amdgcn_global_load_lds((gu32*)g, (lu32*)l, 16, 0, 0);
}

// ---------------- dtype detection ----------------
__global__ void detect_k(const unsigned* __restrict__ x, int* __restrict__ flag) {
  __shared__ int cnt;
  if (threadIdx.x == 0) cnt = 0;
  __syncthreads();
  int c = 0;
#pragma unroll
  for (int i = 0; i < 4; i++) {
    unsigned w = x[threadIdx.x * 4 + i];
    unsigned e = (w >> 7) & 0xFFu;
    if (e < 97u || e > 157u) c++;
  }
  atomicAdd(&cnt, c);
  __syncthreads();
  if (threadIdx.x == 0) flag[0] = (cnt > 256) ? 1 : 0;  // 1 = f32 inputs
}

// ---------------- fused canonicalize: x (vectorized x4) + all small inputs ----------------
__global__ __launch_bounds__(256) void conv_all(const void* x_raw,
                                                const void* qnw_raw, const void* kvnw_raw,
                                                const void* wg_raw, const void* bg_raw,
                                                const void* unc_raw,
                                                bf16* xc, bf16* qnw, bf16* kvnw,
                                                bf16* wgc, bf16* bgc, float* uncf,
                                                const int* flag) {
  bool isf = (*flag != 0);
  if (blockIdx.x < 8192) {
    int i4 = blockIdx.x * 256 + threadIdx.x;   // vector index (4 elems each)
    v4s o;
    if (isf) {
      float4 v = ((const float4*)x_raw)[i4];
      o[0] = f2bfbits(v.x); o[1] = f2bfbits(v.y);
      o[2] = f2bfbits(v.z); o[3] = f2bfbits(v.w);
    } else {
      o = ((const v4s*)x_raw)[i4];
    }
    *reinterpret_cast<v4s*>(xc + (size_t)i4 * 4) = o;
  } else {
    int i = (blockIdx.x - 8192) * 256 + threadIdx.x;
    if (i < 1536) qnw[i] = isf ? __float2bfloat16(((const float*)qnw_raw)[i]) : ((const bf16*)qnw_raw)[i];
    else if (i < 2048) { int j = i - 1536; kvnw[j] = isf ? __float2bfloat16(((const float*)kvnw_raw)[j]) : ((const bf16*)kvnw_raw)[j]; }
    else if (i < 4096) { int j = i - 2048; wgc[j] = isf ? __float2bfloat16(((const float*)wg_raw)[j]) : ((const bf16*)wg_raw)[j]; }
    else if (i < 4097) bgc[0] = isf ? __float2bfloat16(((const float*)bg_raw)[0]) : ((const bf16*)bg_raw)[0];
    else if (i < 8193) { int j = i - 4097; uncf[j] = isf ? ((const float*)unc_raw)[j] : __bfloat162float(((const bf16*)unc_raw)[j]); }
  }
}

// ---------------- all 8 weight transposes in one dispatch ----------------
struct TP8 {
  const void* s[8];
  bf16* d[8];
  int rows[8];
  int cols[8];
  int pre[9];
};

__global__ __launch_bounds__(256) void transpose_all(TP8 jobs, const int* __restrict__ flag) {
  __shared__ bf16 tile[32][33];
  int bid = blockIdx.x;
  int w = 0;
#pragma unroll
  for (int k = 0; k < 7; k++) if (bid >= jobs.pre[k + 1]) w = k + 1;
  int lt = bid - jobs.pre[w];
  int rows = jobs.rows[w], cols = jobs.cols[w];
  int tpr = cols >> 5;
  int by = (lt / tpr) << 5, bx = (lt % tpr) << 5;
  const void* src = jobs.s[w];
  bf16* dst = jobs.d[w];
  int tx = threadIdx.x & 31, ty = threadIdx.x >> 5;
  bool isf = (*flag != 0);
#pragma unroll
  for (int i = 0; i < 32; i += 8) {
    size_t idx = (size_t)(by + ty + i) * cols + bx + tx;
    tile[ty + i][tx] = isf ? __float2bfloat16(((const float*)src)[idx])
                           : ((const bf16*)src)[idx];
  }
  __syncthreads();
#pragma unroll
  for (int i = 0; i < 32; i += 8)
    dst[(size_t)(bx + ty + i) * rows + by + tx] = tile[tx][ty + i];
}

// ---------------- strided bf16 transpose (V^T out of fused kcv) ----------------
__global__ __launch_bounds__(256) void transpose_str(const bf16* __restrict__ src,
                                                     bf16* __restrict__ dst,
                                                     int srcStride, int dstStride) {
  __shared__ bf16 tile[32][33];
  int bx = blockIdx.x * 32, by = blockIdx.y * 32;
  int tx = threadIdx.x & 31, ty = threadIdx.x >> 5;
#pragma unroll
  for (int i = 0; i < 32; i += 8)
    tile[ty + i][tx] = src[(size_t)(by + ty + i) * srcStride + bx + tx];
  __syncthreads();
#pragma unroll
  for (int i = 0; i < 32; i += 8)
    dst[(size_t)(bx + ty + i) * dstStride + by + tx] = tile[tx][ty + i];
}

// ---------------- TN GEMM: C[M,N] = A[M,K] * BT[N,K]^T (DMA staging) ----------------
// If dvout!=nullptr, epilogue writes dvout in detected dtype (*oflag: 1=f32).
__global__ __launch_bounds__(256) void gemm_tn(const bf16* __restrict__ A,
                                               const bf16* __restrict__ BT,
                                               bf16* __restrict__ Cb,
                                               int M, int N, int K,
                                               const int* __restrict__ oflag,
                                               void* __restrict__ dvout) {
  __shared__ __align__(16) short lsa[128 * 32];
  __shared__ __align__(16) short lsb[128 * 32];
  const int m0 = blockIdx.y * 128, n0 = blockIdx.x * 128;
  const int tid = threadIdx.x;
  const int w = tid >> 6, lane = tid & 63, quad = lane >> 4, l16 = lane & 15;
  const int wm = (w >> 1) * 64, wn = (w & 1) * 64;
  const int srow = ((lane >> 5) & 1) * 8 + (lane & 7);
  const int skq  = (lane >> 3) & 3;
  const int r0 = w * 2, r1 = w * 2 + 1;
  const bf16* Ab0 = A  + (size_t)(m0 + r0 * 16 + srow) * K + skq * 8;
  const bf16* Ab1 = A  + (size_t)(m0 + r1 * 16 + srow) * K + skq * 8;
  const bf16* Bb0 = BT + (size_t)(n0 + r0 * 16 + srow) * K + skq * 8;
  const bf16* Bb1 = BT + (size_t)(n0 + r1 * 16 + srow) * K + skq * 8;
  short* la0 = &lsa[r0 * 512];
  short* la1 = &lsa[r1 * 512];
  short* lb0 = &lsb[r0 * 512];
  short* lb1 = &lsb[r1 * 512];

  v4f acc[4][4];
#pragma unroll
  for (int i = 0; i < 4; i++)
#pragma unroll
    for (int j = 0; j < 4; j++) acc[i][j] = (v4f){0.f, 0.f, 0.f, 0.f};

  for (int kb = 0; kb < K; kb += 32) {
    __syncthreads();
    gl_lds16(Ab0 + kb, la0);
    gl_lds16(Ab1 + kb, la1);
    gl_lds16(Bb0 + kb, lb0);
    gl_lds16(Bb1 + kb, lb1);
    __syncthreads();

    v8bf af[4], bfr[4];
#pragma unroll
    for (int i = 0; i < 4; i++) {
      int row = wm + i * 16 + l16;
      af[i] = *reinterpret_cast<const v8bf*>(
          &lsa[((row >> 3) << 8) + (quad << 6) + ((row & 7) << 3)]);
    }
#pragma unroll
    for (int j = 0; j < 4; j++) {
      int row = wn + j * 16 + l16;
      bfr[j] = *reinterpret_cast<const v8bf*>(
          &lsb[((row >> 3) << 8) + (quad << 6) + ((row & 7) << 3)]);
    }
#pragma unroll
    for (int i = 0; i < 4; i++)
#pragma unroll
      for (int j = 0; j < 4; j++)
        acc[i][j] = __builtin_amdgcn_mfma_f32_16x16x32_bf16(af[i], bfr[j], acc[i][j], 0, 0, 0);
  }
  const bool isf = dvout && (*oflag != 0);
#pragma unroll
  for (int i = 0; i < 4; i++)
#pragma unroll
    for (int j = 0; j < 4; j++)
#pragma unroll
      for (int r = 0; r < 4; r++) {
        int row = m0 + wm + i * 16 + quad * 4 + r;
        int col = n0 + wn + j * 16 + l16;
        float vv = acc[i][j][r];
        size_t idx = (size_t)row * N + col;
        if (dvout) {
          if (isf) ((float*)dvout)[idx] = vv;
          else     ((bf16*)dvout)[idx] = __float2bfloat16(vv);
        } else {
          Cb[idx] = __float2bfloat16(vv);
        }
      }
}

// ---------------- both RMS norms in one dispatch ----------------
__global__ __launch_bounds__(256) void rmsnorm_both(const bf16* __restrict__ xproj,
                                                    const bf16* __restrict__ qnw,
                                                    const bf16* __restrict__ kvnw,
                                                    bf16* __restrict__ q_lat,
                                                    bf16* __restrict__ kv_lat) {
  int bid = blockIdx.x, tid = threadIdx.x;
  bool isq = bid < 4096;
  int row = isq ? bid : bid - 4096;
  int C = isq ? 1536 : 512;
  const bf16* r = xproj + (size_t)row * 3072 + (isq ? 0 : 1536);
  const bf16* w = isq ? qnw : kvnw;
  bf16* o = (isq ? q_lat : kv_lat) + (size_t)row * C;
  float s = 0.f;
  for (int i = tid; i < C; i += 256) { float v = __bfloat162float(r[i]); s += v * v; }
#pragma unroll
  for (int m = 32; m; m >>= 1) s += __shfl_xor(s, m);
  __shared__ float red[4];
  if ((tid & 63) == 0) red[tid >> 6] = s;
  __syncthreads();
  float tot = red[0] + red[1] + red[2] + red[3];
  float rs = rsqrtf(tot / (float)C + 1e-6f);
  for (int i = tid; i < C; i += 256)
    o[i] = __float2bfloat16(__bfloat162float(r[i]) * rs * __bfloat162float(w[i]));
}

// ---------------- rope (q_r in qcr, k_r in xproj) + gate (writes d_out alpha) ----------------
__global__ __launch_bounds__(256) void rope_gate(bf16* __restrict__ qcr,
                                                 bf16* __restrict__ xproj,
                                                 const float* __restrict__ unc,
                                                 const bf16* __restrict__ x,
                                                 const bf16* __restrict__ wg,
                                                 const bf16* __restrict__ bg,
                                                 float* __restrict__ af,
                                                 void* __restrict__ dout,
                                                 const int* __restrict__ flag) {
  __shared__ float red[4];
  int tid = threadIdx.x;
  if (blockIdx.x < 8192) {
    int idx = blockIdx.x * 256 + tid;
    int j = idx & 31, h = (idx >> 5) & 15, bt = idx >> 9;
    int t = bt & (T_SEQ - 1);
    float u = unc[bt];
    u = fminf(fmaxf(u, 0.f), 1.f);
    float scale = 0.5f + 1.5f * u;
    float theta = expf(-(float)j * (1.f / 32.f) * logf(500000.f));
    float f = (float)t * theta * scale;
    float c = cosf(f), s = sinf(f);
    size_t base = (size_t)bt * 3072 + 2048 + h * RDIM + j;
    {
      float x1 = __bfloat162float(qcr[base]), x2 = __bfloat162float(qcr[base + 32]);
      qcr[base]      = __float2bfloat16(x1 * c - x2 * s);
      qcr[base + 32] = __float2bfloat16(x2 * c + x1 * s);
    }
    {
      float x1 = __bfloat162float(xproj[base]), x2 = __bfloat162float(xproj[base + 32]);
      xproj[base]      = __float2bfloat16(x1 * c - x2 * s);
      xproj[base + 32] = __float2bfloat16(x2 * c + x1 * s);
    }
  } else {
    int row = blockIdx.x - 8192;
    const bf16* xr = x + (size_t)row * DMODEL;
    float s = 0.f;
    for (int i = tid; i < DMODEL; i += 256)
      s += __bfloat162float(xr[i]) * __bfloat162float(wg[i]);
#pragma unroll
    for (int m = 32; m; m >>= 1) s += __shfl_xor(s, m);
    if ((tid & 63) == 0) red[tid >> 6] = s;
    __syncthreads();
    if (tid == 0) {
      float tot = red[0] + red[1] + red[2] + red[3] + __bfloat162float(bg[0]);
      float a = 1.f / (1.f + expf(-tot));
      af[row] = a;
      size_t oi = (size_t)8388608 + row;   // alpha region of d_out
      if (*flag) ((float*)dout)[oi] = a;
      else       ((bf16*)dout)[oi] = __float2bfloat16(a);
    }
  }
}

// ---------------- fused flash attention: bidir + windowed-causal AR, one pass ----------------
// 256 threads / 4 waves, Q-tile 128 (32 rows/wave), K-tile 64, 32x32 MFMA,
// swapped operands (S^T = K·Q^T, O^T = V^T·P^T), lane-local softmax, P via
// pack+permlane32_swap. NATURAL tile order kb=0..2047: all 16 qt-blocks of a
// (b,h) pair sweep K/V in lockstep on ONE XCD (decode below) -> K/V served
// from that XCD's L2 (round-3-proven: FETCH 44.5 MB). AR via arp round-trip
// snapshot (no snapshot registers -> no spill): at kb==klo store raw oacc to
// arp (volatile, blocks store-to-load forwarding); at the wave's diagonal
// tile reload, AR=(oacc-prev)·(1-a)/l_ar, overwrite in place; epilogue adds.
// T14: next tile's global loads issued into regs before compute.
__global__ __launch_bounds__(256, 2) void attn_f(const bf16* __restrict__ qcr,
                                                 const bf16* __restrict__ kcv,
                                                 const bf16* __restrict__ xproj,
                                                 const bf16* __restrict__ vt,
                                                 const float* __restrict__ alphaF,
                                                 float* __restrict__ arp,
                                                 bf16* __restrict__ out) {
  constexpr int LDK = 200;  // 192 + pad
  constexpr int LDV = 72;   // 64 + pad
  __shared__ __align__(16) short sh[64 * LDK + 128 * LDV];  // 44032 B
  short* lk  = sh;
  short* lvt = sh + 64 * LDK;

  // XCD-pair-colocating decode (HW: XCD = flat % 8)
  const int f_ = blockIdx.x;
  const int xcd = f_ & 7, g_ = f_ >> 3;
  const int qt = g_ & 15;
  const int p_ = xcd + 8 * (g_ >> 4);
  const int h = p_ & 15, b = p_ >> 4;

  const int qs = qt * 128;
  const int tid = threadIdx.x;
  const int w = tid >> 6, lane = tid & 63;
  const int l5 = lane & 31, h8 = lane >> 5;
  const int q0 = qs + w * 32;
  const int myq = q0 + l5;   // this lane's q row (S^T column)

  // Q fragments (B-operand: col=lane&31, k=(lane>>5)*8+v)
  v8bf qf[12];
  {
    const bf16* qcb = qcr + ((size_t)b * T_SEQ + myq) * 3072 + h * HDIM;
#pragma unroll
    for (int ks = 0; ks < 8; ks++)
      qf[ks] = *reinterpret_cast<const v8bf*>(qcb + ks * 16 + h8 * 8);
    const bf16* qrb = qcr + ((size_t)b * T_SEQ + myq) * 3072 + 2048 + h * RDIM;
#pragma unroll
    for (int ks = 0; ks < 4; ks++)
      qf[8 + ks] = *reinterpret_cast<const v8bf*>(qrb + ks * 16 + h8 * 8);
  }

  float l_sum = 0.f, l_snap = 0.f;
  f32x16 oacc[4];
#pragma unroll
  for (int nd = 0; nd < 4; nd++)
#pragma unroll
    for (int r = 0; r < 16; r++) oacc[nd][r] = 0.f;

  const float a_q = alphaF[b * T_SEQ + myq];
  const float sc = 0.07216878364870323f;  // 1/sqrt(192)

  const int c_ = qs >> 8;
  const int klo  = (c_ > 0) ? (c_ * 256 - 256) : 0;  // AR window start (64-aligned)
  const int kb_d = qs + (w >> 1) * 64;                // wave's diagonal tile

  // per-lane arp base: arp[((b,h,d))][q] with q=myq; d varies per store
  volatile float* arp_v = arp + (size_t)((b * NHEADS + h) * HDIM) * T_SEQ + myq;

  // staging bases (affine per-chunk offsets)
  const int koc0 = (tid >> 4) * 4096 + (tid & 15) * 8;
  const int ldc0 = (tid >> 4) * LDK  + (tid & 15) * 8;
  const int kor0 = (tid >> 3) * 3072 + (tid & 7) * 8;
  const int ldr0 = (tid >> 3) * LDK + 128 + (tid & 7) * 8;
  const int kov0 = (tid >> 3) * 4096 + (tid & 7) * 8;
  const int ldv0 = (tid >> 3) * LDV  + (tid & 7) * 8;
  const bf16* kc_base = kcv   + (size_t)b * T_SEQ * 4096 + h * HDIM;
  const bf16* kr_base = xproj + (size_t)b * T_SEQ * 3072 + 2048 + h * RDIM;
  const bf16* v_base  = vt    + (size_t)h * HDIM * (2 * T_SEQ) + b * T_SEQ;

  v4u rc[4], rr[2], rv[4];
  auto issue = [&](int kb) {
    const bf16* pc = kc_base + (size_t)kb * 4096;
    const bf16* pr = kr_base + (size_t)kb * 3072;
    const bf16* pv = v_base + kb;
#pragma unroll
    for (int i = 0; i < 4; i++) rc[i] = *reinterpret_cast<const v4u*>(pc + koc0 + i * 65536);
#pragma unroll
    for (int i = 0; i < 2; i++) rr[i] = *reinterpret_cast<const v4u*>(pr + kor0 + i * 98304);
#pragma unroll
    for (int i = 0; i < 4; i++) rv[i] = *reinterpret_cast<const v4u*>(pv + kov0 + i * 131072);
  };

  auto qk = [&](int j) -> f32x16 {
    f32x16 s;
#pragma unroll
    for (int r = 0; r < 16; r++) s[r] = 0.f;
#pragma unroll
    for (int ks = 0; ks < 12; ks++) {
      v8bf kf = *reinterpret_cast<const v8bf*>(&lk[(j * 32 + l5) * LDK + ks * 16 + h8 * 8]);
      s = __builtin_amdgcn_mfma_f32_32x32x16_bf16(kf, qf[ks], s, 0, 0, 0);
    }
    return s;
  };
  auto pack8 = [&](const float* p) -> v8bf {
    unsigned Y0 = pk2bf(p[0], p[1]);
    unsigned Y1 = pk2bf(p[2], p[3]);
    unsigned Y2 = pk2bf(p[4], p[5]);
    unsigned Y3 = pk2bf(p[6], p[7]);
    asm volatile("v_permlane32_swap_b32 %0, %1" : "+v"(Y0), "+v"(Y2));
    asm volatile("v_permlane32_swap_b32 %0, %1" : "+v"(Y1), "+v"(Y3));
    v4u t; t.x = Y0; t.y = Y1; t.z = Y2; t.w = Y3;
    return __builtin_bit_cast(v8bf, t);
  };
  auto pvj = [&](int j, const v8bf* pf) {
#pragma unroll
    for (int ck = 0; ck < 2; ck++)
#pragma unroll
      for (int nd = 0; nd < 4; nd++) {
        v8bf vf = *reinterpret_cast<const v8bf*>(&lvt[(nd * 32 + l5) * LDV + (j * 2 + ck) * 16 + h8 * 8]);
        oacc[nd] = __builtin_amdgcn_mfma_f32_32x32x16_bf16(vf, pf[ck], oacc[nd], 0, 0, 0);
      }
  };
  auto plainpass = [&](int j) {
    f32x16 s = qk(j);
    v8bf pf[2];
#pragma unroll
    for (int cc = 0; cc < 2; cc++) {
      float p[8];
#pragma unroll
      for (int r8 = 0; r8 < 8; r8++) {
        float e = __expf(s[cc * 8 + r8] * sc);
        p[r8] = e;
        l_sum += e;
      }
      pf[cc] = pack8(p);
    }
    pvj(j, pf);
  };
  auto maskpass = [&](int j, int kb, bool upper) {
    f32x16 s = qk(j);
    v8bf pf[2];
#pragma unroll
    for (int cc = 0; cc < 2; cc++) {
      float p[8];
#pragma unroll
      for (int r8 = 0; r8 < 8; r8++) {
        int r = cc * 8 + r8;
        int kk = kb + j * 32 + (r & 3) + 8 * (r >> 2) + 4 * h8;
        float e = __expf(s[r] * sc);
        bool keep = upper ? (kk > myq) : (kk <= myq);
        e = keep ? e : 0.f;
        p[r8] = e;
        l_sum += e;
      }
      pf[cc] = pack8(p);
    }
    pvj(j, pf);
  };

  issue(0);

  for (int kb = 0; kb < T_SEQ; kb += 64) {
    __syncthreads();  // WAR: all waves done reading previous tile
    // commit prefetched tile to LDS (compiler inserts vmcnt waits)
#pragma unroll
    for (int i = 0; i < 4; i++) *reinterpret_cast<v4u*>(&lk[ldc0 + i * 16 * LDK]) = rc[i];
#pragma unroll
    for (int i = 0; i < 2; i++) *reinterpret_cast<v4u*>(&lk[ldr0 + i * 32 * LDK]) = rr[i];
#pragma unroll
    for (int i = 0; i < 4; i++) *reinterpret_cast<v4u*>(&lvt[ldv0 + i * 32 * LDV]) = rv[i];
    if (kb + 64 < T_SEQ) issue(kb + 64);  // loads stay in flight across compute
    __syncthreads();

    if (kb == klo) {  // snapshot pre-window state to arp (raw, unscaled)
#pragma unroll
      for (int nd = 0; nd < 4; nd++)
#pragma unroll
        for (int r = 0; r < 16; r++) {
          int d = nd * 32 + (r & 3) + 8 * (r >> 2) + 4 * h8;
          arp_v[(size_t)d * T_SEQ] = oacc[nd][r];
        }
      l_snap = l_sum;
    }

    __builtin_amdgcn_s_setprio(1);
    if (kb != kb_d) {
      plainpass(0);
      plainpass(1);
    } else {
      // diagonal tile: lower-masked completes AR window; extract AR; complement
      maskpass(0, kb, false);
      maskpass(1, kb, false);
      {
        float lar_h = l_sum - l_snap;
        float lar = lar_h + __shfl_xor(lar_h, 32);
        float sAR = (1.f - a_q) / lar;
#pragma unroll
        for (int nd = 0; nd < 4; nd++)
#pragma unroll
          for (int r = 0; r < 16; r++) {
            int d = nd * 32 + (r & 3) + 8 * (r >> 2) + 4 * h8;
            float prev = arp_v[(size_t)d * T_SEQ];
            arp_v[(size_t)d * T_SEQ] = (oacc[nd][r] - prev) * sAR;
          }
      }
      maskpass(0, kb, true);
      maskpass(1, kb, true);
    }
    __builtin_amdgcn_s_setprio(0);
  }

  // combine softmax denominator across lane halves
  l_sum += __shfl_xor(l_sum, 32);
  float inv = a_q / l_sum;

  // epilogue: merged = a·O_b/l_b + (1-a)·O_ar/l_ar, O^T -> LDS -> coalesced store
  __syncthreads();  // all waves done with lk/lvt
  short* tile = sh + w * (32 * 136);
  const float* arpb = arp + (size_t)((b * NHEADS + h) * HDIM) * T_SEQ + myq;
#pragma unroll
  for (int nd = 0; nd < 4; nd++)
#pragma unroll
    for (int rg = 0; rg < 4; rg++) {
      v4s pk;
#pragma unroll
      for (int i = 0; i < 4; i++) {
        int d = nd * 32 + rg * 8 + h8 * 4 + i;
        float val = oacc[nd][rg * 4 + i] * inv + arpb[(size_t)d * T_SEQ];
        pk[i] = f2bfbits(val);
      }
      // d = nd*32 + rg*8 + h8*4 + i  (C/D row formula), q = l5
      *reinterpret_cast<v4s*>(&tile[l5 * 136 + nd * 32 + rg * 8 + h8 * 4]) = pk;
    }
  __syncthreads();
#pragma unroll
  for (int i = 0; i < 8; i++) {
    int r = i * 4 + (lane >> 4);
    int q2 = qs + w * 32 + r;
    int dcol = (lane & 15) * 8;
    v8s mv = *reinterpret_cast<const v8s*>(&tile[r * 136 + dcol]);
    size_t gbase = ((size_t)b * T_SEQ + q2) * DMODEL + h * HDIM + dcol;
    *reinterpret_cast<v8s*>((void*)(out + gbase)) = mv;
  }
}

extern "C" void kernel_launch(void* const* d_in, const int* in_sizes, int n_in,
                              void* d_out, int out_size, void* d_ws, size_t ws_size,
                              hipStream_t stream) {
  const void* x_raw    = d_in[0];
  const void* unc_raw  = d_in[1];
  const void* Wqd_raw  = d_in[2];
  const void* qnw_raw  = d_in[3];
  const void* Wqu_raw  = d_in[4];
  const void* Wqr_raw  = d_in[5];
  const void* Wkvd_raw = d_in[6];
  const void* kvnw_raw = d_in[7];
  const void* Wku_raw  = d_in[8];
  const void* Wvu_raw  = d_in[9];
  const void* Wkr_raw  = d_in[10];
  const void* Wo_raw   = d_in[11];
  const void* Wg_raw   = d_in[12];
  const void* bg_raw   = d_in[13];

  char* ws = (char*)d_ws;
  size_t off = 0;
  auto alloc = [&](size_t bytes) -> void* {
    char* p = ws + off;
    off += (bytes + 255) & ~(size_t)255;
    return p;
  };
  int*  flag   = (int*)alloc(256);
  bf16* xc     = (bf16*)alloc((size_t)4096 * 2048 * 2);
  float* uncf  = (float*)alloc((size_t)4096 * 4);
  bf16* qnw    = (bf16*)alloc(1536 * 2);
  bf16* kvnw   = (bf16*)alloc(512 * 2);
  bf16* wgc    = (bf16*)alloc(2048 * 2);
  bf16* bgc    = (bf16*)alloc(256);
  bf16* BT1    = (bf16*)alloc((size_t)3072 * 2048 * 2);  // [WqdT;WkvdT;WkrT], K=2048
  bf16* BT2    = (bf16*)alloc((size_t)3072 * 1536 * 2);  // [WquT;WqrT], K=1536
  bf16* BT3    = (bf16*)alloc((size_t)4096 * 512 * 2);   // [WkuT;WvuT], K=512
  bf16* WoT    = (bf16*)alloc((size_t)2048 * 2048 * 2);
  bf16* xproj  = (bf16*)alloc((size_t)4096 * 3072 * 2);  // [q_raw|kv_raw|k_r]
  bf16* q_lat  = (bf16*)alloc((size_t)4096 * 1536 * 2);
  bf16* kv_lat = (bf16*)alloc((size_t)4096 * 512 * 2);
  bf16* qcr    = (bf16*)alloc((size_t)4096 * 3072 * 2);  // [q_c|q_r]
  bf16* kcv    = (bf16*)alloc((size_t)4096 * 4096 * 2);  // [k_c|v]
  bf16* vT     = (bf16*)alloc((size_t)4096 * 2048 * 2);
  float* arp   = (float*)alloc((size_t)2 * NHEADS * HDIM * T_SEQ * 4);  // AR scratch, f32
  bf16* attno  = (bf16*)alloc((size_t)4096 * 2048 * 2);  // merged attention out
  float* alphaF= (float*)alloc((size_t)4096 * 4);

  detect_k<<<1, 256, 0, stream>>>((const unsigned*)x_raw, flag);

  conv_all<<<8225, 256, 0, stream>>>(x_raw, qnw_raw, kvnw_raw, Wg_raw, bg_raw, unc_raw,
                                     xc, qnw, kvnw, wgc, bgc, uncf, flag);

  // one dispatch for all 8 weight transposes
  TP8 jobs;
  const void* srcs[8] = {Wqd_raw, Wkvd_raw, Wkr_raw, Wqu_raw, Wqr_raw, Wku_raw, Wvu_raw, Wo_raw};
  bf16* dsts[8] = {BT1, BT1 + (size_t)1536 * 2048, BT1 + (size_t)2048 * 2048,
                   BT2, BT2 + (size_t)2048 * 1536,
                   BT3, BT3 + (size_t)2048 * 512, WoT};
  int rws[8] = {2048, 2048, 2048, 1536, 1536, 512, 512, 2048};
  int cls[8] = {1536, 512, 1024, 2048, 1024, 2048, 2048, 2048};
  int acc_t = 0;
  for (int i = 0; i < 8; i++) {
    jobs.s[i] = srcs[i]; jobs.d[i] = dsts[i];
    jobs.rows[i] = rws[i]; jobs.cols[i] = cls[i];
    jobs.pre[i] = acc_t;
    acc_t += (rws[i] / 32) * (cls[i] / 32);
  }
  jobs.pre[8] = acc_t;
  transpose_all<<<acc_t, 256, 0, stream>>>(jobs, flag);

  auto gemmb = [&](const bf16* A, const bf16* BT, bf16* C, int M, int N, int K) {
    gemm_tn<<<dim3(N / 128, M / 128), 256, 0, stream>>>(A, BT, C, M, N, K, nullptr, nullptr);
  };

  gemmb(xc, BT1, xproj, 4096, 3072, 2048);                 // [q_raw|kv_raw|k_r]
  rmsnorm_both<<<8192, 256, 0, stream>>>(xproj, qnw, kvnw, q_lat, kv_lat);
  gemmb(q_lat, BT2, qcr, 4096, 3072, 1536);                // [q_c|q_r]
  gemmb(kv_lat, BT3, kcv, 4096, 4096, 512);                // [k_c|v]

  // V^T: vT[d][b*T+t] from kcv cols 2048..4095
  transpose_str<<<dim3(64, 128), 256, 0, stream>>>(kcv + 2048, vT, 4096, 4096);

  rope_gate<<<12288, 256, 0, stream>>>(qcr, xproj, uncf, xc, wgc, bgc, alphaF, d_out, flag);

  // single fused attention (bidir + AR + alpha-merge), XCD-pair-colocated flat grid
  attn_f<<<512, 256, 0, stream>>>(qcr, kcv, xproj, vT, alphaF, arp, attno);

  // final projection writes d_out directly in detected dtype
  gemm_tn<<<dim3(16, 32), 256, 0, stream>>>(attno, WoT, nullptr, 4096, 2048, 2048, flag, d_out);

  (void)in_sizes; (void)n_in; (void)out_size; (void)ws_size;
}

// Round 6
// 640.919 us; speedup vs baseline: 1.2687x; 1.2687x over previous
//
#include <hip/hip_runtime.h>
#include <hip/hip_bf16.h>
#include <math.h>

typedef __hip_bfloat16 bf16;
using v8bf = __attribute__((ext_vector_type(8))) __bf16;
using v4f  = __attribute__((ext_vector_type(4))) float;
using f32x16 = __attribute__((ext_vector_type(16))) float;
using v4u = __attribute__((ext_vector_type(4))) unsigned;
using v4s = __attribute__((ext_vector_type(4))) short;
using v8s = __attribute__((ext_vector_type(8))) short;

#define T_SEQ 2048
#define DMODEL 2048
#define NHEADS 16
#define HDIM 128
#define RDIM 64

__device__ __forceinline__ short f2bfbits(float f) {
  bf16 h = __float2bfloat16(f);
  short s;
  __builtin_memcpy(&s, &h, 2);
  return s;
}

__device__ __forceinline__ unsigned pk2bf(float a, float b) {
  unsigned lo = (unsigned short)f2bfbits(a);
  unsigned hi = (unsigned short)f2bfbits(b);
  return lo | (hi << 16);
}

// async global->LDS, 16B per lane (GEMM staging only)
typedef const __attribute__((address_space(1))) unsigned gu32;
typedef __attribute__((address_space(3))) unsigned lu32;
__device__ __forceinline__ void gl_lds16(const void* g, void* l) {
  __builtin_amdgcn_global_load_lds((gu32*)g, (lu32*)l, 16, 0, 0);
}

// ---------------- dtype detection ----------------
__global__ void detect_k(const unsigned* __restrict__ x, int* __restrict__ flag) {
  __shared__ int cnt;
  if (threadIdx.x == 0) cnt = 0;
  __syncthreads();
  int c = 0;
#pragma unroll
  for (int i = 0; i < 4; i++) {
    unsigned w = x[threadIdx.x * 4 + i];
    unsigned e = (w >> 7) & 0xFFu;
    if (e < 97u || e > 157u) c++;
  }
  atomicAdd(&cnt, c);
  __syncthreads();
  if (threadIdx.x == 0) flag[0] = (cnt > 256) ? 1 : 0;  // 1 = f32 inputs
}

// ---------------- fused canonicalize: x (vectorized x4) + all small inputs ----------------
__global__ __launch_bounds__(256) void conv_all(const void* x_raw,
                                                const void* qnw_raw, const void* kvnw_raw,
                                                const void* wg_raw, const void* bg_raw,
                                                const void* unc_raw,
                                                bf16* xc, bf16* qnw, bf16* kvnw,
                                                bf16* wgc, bf16* bgc, float* uncf,
                                                const int* flag) {
  bool isf = (*flag != 0);
  if (blockIdx.x < 8192) {
    int i4 = blockIdx.x * 256 + threadIdx.x;   // vector index (4 elems each)
    v4s o;
    if (isf) {
      float4 v = ((const float4*)x_raw)[i4];
      o[0] = f2bfbits(v.x); o[1] = f2bfbits(v.y);
      o[2] = f2bfbits(v.z); o[3] = f2bfbits(v.w);
    } else {
      o = ((const v4s*)x_raw)[i4];
    }
    *reinterpret_cast<v4s*>(xc + (size_t)i4 * 4) = o;
  } else {
    int i = (blockIdx.x - 8192) * 256 + threadIdx.x;
    if (i < 1536) qnw[i] = isf ? __float2bfloat16(((const float*)qnw_raw)[i]) : ((const bf16*)qnw_raw)[i];
    else if (i < 2048) { int j = i - 1536; kvnw[j] = isf ? __float2bfloat16(((const float*)kvnw_raw)[j]) : ((const bf16*)kvnw_raw)[j]; }
    else if (i < 4096) { int j = i - 2048; wgc[j] = isf ? __float2bfloat16(((const float*)wg_raw)[j]) : ((const bf16*)wg_raw)[j]; }
    else if (i < 4097) bgc[0] = isf ? __float2bfloat16(((const float*)bg_raw)[0]) : ((const bf16*)bg_raw)[0];
    else if (i < 8193) { int j = i - 4097; uncf[j] = isf ? ((const float*)unc_raw)[j] : __bfloat162float(((const bf16*)unc_raw)[j]); }
  }
}

// ---------------- all 8 weight transposes in one dispatch ----------------
struct TP8 {
  const void* s[8];
  bf16* d[8];
  int rows[8];
  int cols[8];
  int pre[9];
};

__global__ __launch_bounds__(256) void transpose_all(TP8 jobs, const int* __restrict__ flag) {
  __shared__ bf16 tile[32][33];
  int bid = blockIdx.x;
  int w = 0;
#pragma unroll
  for (int k = 0; k < 7; k++) if (bid >= jobs.pre[k + 1]) w = k + 1;
  int lt = bid - jobs.pre[w];
  int rows = jobs.rows[w], cols = jobs.cols[w];
  int tpr = cols >> 5;
  int by = (lt / tpr) << 5, bx = (lt % tpr) << 5;
  const void* src = jobs.s[w];
  bf16* dst = jobs.d[w];
  int tx = threadIdx.x & 31, ty = threadIdx.x >> 5;
  bool isf = (*flag != 0);
#pragma unroll
  for (int i = 0; i < 32; i += 8) {
    size_t idx = (size_t)(by + ty + i) * cols + bx + tx;
    tile[ty + i][tx] = isf ? __float2bfloat16(((const float*)src)[idx])
                           : ((const bf16*)src)[idx];
  }
  __syncthreads();
#pragma unroll
  for (int i = 0; i < 32; i += 8)
    dst[(size_t)(bx + ty + i) * rows + by + tx] = tile[tx][ty + i];
}

// ---------------- strided bf16 transpose (V^T out of fused kcv) ----------------
__global__ __launch_bounds__(256) void transpose_str(const bf16* __restrict__ src,
                                                     bf16* __restrict__ dst,
                                                     int srcStride, int dstStride) {
  __shared__ bf16 tile[32][33];
  int bx = blockIdx.x * 32, by = blockIdx.y * 32;
  int tx = threadIdx.x & 31, ty = threadIdx.x >> 5;
#pragma unroll
  for (int i = 0; i < 32; i += 8)
    tile[ty + i][tx] = src[(size_t)(by + ty + i) * srcStride + bx + tx];
  __syncthreads();
#pragma unroll
  for (int i = 0; i < 32; i += 8)
    dst[(size_t)(bx + ty + i) * dstStride + by + tx] = tile[tx][ty + i];
}

// ---------------- TN GEMM: C[M,N] = A[M,K] * BT[N,K]^T (DMA staging) ----------------
// If dvout!=nullptr, epilogue writes dvout in detected dtype (*oflag: 1=f32).
__global__ __launch_bounds__(256) void gemm_tn(const bf16* __restrict__ A,
                                               const bf16* __restrict__ BT,
                                               bf16* __restrict__ Cb,
                                               int M, int N, int K,
                                               const int* __restrict__ oflag,
                                               void* __restrict__ dvout) {
  __shared__ __align__(16) short lsa[128 * 32];
  __shared__ __align__(16) short lsb[128 * 32];
  const int m0 = blockIdx.y * 128, n0 = blockIdx.x * 128;
  const int tid = threadIdx.x;
  const int w = tid >> 6, lane = tid & 63, quad = lane >> 4, l16 = lane & 15;
  const int wm = (w >> 1) * 64, wn = (w & 1) * 64;
  const int srow = ((lane >> 5) & 1) * 8 + (lane & 7);
  const int skq  = (lane >> 3) & 3;
  const int r0 = w * 2, r1 = w * 2 + 1;
  const bf16* Ab0 = A  + (size_t)(m0 + r0 * 16 + srow) * K + skq * 8;
  const bf16* Ab1 = A  + (size_t)(m0 + r1 * 16 + srow) * K + skq * 8;
  const bf16* Bb0 = BT + (size_t)(n0 + r0 * 16 + srow) * K + skq * 8;
  const bf16* Bb1 = BT + (size_t)(n0 + r1 * 16 + srow) * K + skq * 8;
  short* la0 = &lsa[r0 * 512];
  short* la1 = &lsa[r1 * 512];
  short* lb0 = &lsb[r0 * 512];
  short* lb1 = &lsb[r1 * 512];

  v4f acc[4][4];
#pragma unroll
  for (int i = 0; i < 4; i++)
#pragma unroll
    for (int j = 0; j < 4; j++) acc[i][j] = (v4f){0.f, 0.f, 0.f, 0.f};

  for (int kb = 0; kb < K; kb += 32) {
    __syncthreads();
    gl_lds16(Ab0 + kb, la0);
    gl_lds16(Ab1 + kb, la1);
    gl_lds16(Bb0 + kb, lb0);
    gl_lds16(Bb1 + kb, lb1);
    __syncthreads();

    v8bf af[4], bfr[4];
#pragma unroll
    for (int i = 0; i < 4; i++) {
      int row = wm + i * 16 + l16;
      af[i] = *reinterpret_cast<const v8bf*>(
          &lsa[((row >> 3) << 8) + (quad << 6) + ((row & 7) << 3)]);
    }
#pragma unroll
    for (int j = 0; j < 4; j++) {
      int row = wn + j * 16 + l16;
      bfr[j] = *reinterpret_cast<const v8bf*>(
          &lsb[((row >> 3) << 8) + (quad << 6) + ((row & 7) << 3)]);
    }
#pragma unroll
    for (int i = 0; i < 4; i++)
#pragma unroll
      for (int j = 0; j < 4; j++)
        acc[i][j] = __builtin_amdgcn_mfma_f32_16x16x32_bf16(af[i], bfr[j], acc[i][j], 0, 0, 0);
  }
  const bool isf = dvout && (*oflag != 0);
#pragma unroll
  for (int i = 0; i < 4; i++)
#pragma unroll
    for (int j = 0; j < 4; j++)
#pragma unroll
      for (int r = 0; r < 4; r++) {
        int row = m0 + wm + i * 16 + quad * 4 + r;
        int col = n0 + wn + j * 16 + l16;
        float vv = acc[i][j][r];
        size_t idx = (size_t)row * N + col;
        if (dvout) {
          if (isf) ((float*)dvout)[idx] = vv;
          else     ((bf16*)dvout)[idx] = __float2bfloat16(vv);
        } else {
          Cb[idx] = __float2bfloat16(vv);
        }
      }
}

// ---------------- both RMS norms in one dispatch ----------------
__global__ __launch_bounds__(256) void rmsnorm_both(const bf16* __restrict__ xproj,
                                                    const bf16* __restrict__ qnw,
                                                    const bf16* __restrict__ kvnw,
                                                    bf16* __restrict__ q_lat,
                                                    bf16* __restrict__ kv_lat) {
  int bid = blockIdx.x, tid = threadIdx.x;
  bool isq = bid < 4096;
  int row = isq ? bid : bid - 4096;
  int C = isq ? 1536 : 512;
  const bf16* r = xproj + (size_t)row * 3072 + (isq ? 0 : 1536);
  const bf16* w = isq ? qnw : kvnw;
  bf16* o = (isq ? q_lat : kv_lat) + (size_t)row * C;
  float s = 0.f;
  for (int i = tid; i < C; i += 256) { float v = __bfloat162float(r[i]); s += v * v; }
#pragma unroll
  for (int m = 32; m; m >>= 1) s += __shfl_xor(s, m);
  __shared__ float red[4];
  if ((tid & 63) == 0) red[tid >> 6] = s;
  __syncthreads();
  float tot = red[0] + red[1] + red[2] + red[3];
  float rs = rsqrtf(tot / (float)C + 1e-6f);
  for (int i = tid; i < C; i += 256)
    o[i] = __float2bfloat16(__bfloat162float(r[i]) * rs * __bfloat162float(w[i]));
}

// ---------------- rope (q_r in qcr, k_r in xproj) + gate (writes d_out alpha) ----------------
__global__ __launch_bounds__(256) void rope_gate(bf16* __restrict__ qcr,
                                                 bf16* __restrict__ xproj,
                                                 const float* __restrict__ unc,
                                                 const bf16* __restrict__ x,
                                                 const bf16* __restrict__ wg,
                                                 const bf16* __restrict__ bg,
                                                 float* __restrict__ af,
                                                 void* __restrict__ dout,
                                                 const int* __restrict__ flag) {
  __shared__ float red[4];
  int tid = threadIdx.x;
  if (blockIdx.x < 8192) {
    int idx = blockIdx.x * 256 + tid;
    int j = idx & 31, h = (idx >> 5) & 15, bt = idx >> 9;
    int t = bt & (T_SEQ - 1);
    float u = unc[bt];
    u = fminf(fmaxf(u, 0.f), 1.f);
    float scale = 0.5f + 1.5f * u;
    float theta = expf(-(float)j * (1.f / 32.f) * logf(500000.f));
    float f = (float)t * theta * scale;
    float c = cosf(f), s = sinf(f);
    size_t base = (size_t)bt * 3072 + 2048 + h * RDIM + j;
    {
      float x1 = __bfloat162float(qcr[base]), x2 = __bfloat162float(qcr[base + 32]);
      qcr[base]      = __float2bfloat16(x1 * c - x2 * s);
      qcr[base + 32] = __float2bfloat16(x2 * c + x1 * s);
    }
    {
      float x1 = __bfloat162float(xproj[base]), x2 = __bfloat162float(xproj[base + 32]);
      xproj[base]      = __float2bfloat16(x1 * c - x2 * s);
      xproj[base + 32] = __float2bfloat16(x2 * c + x1 * s);
    }
  } else {
    int row = blockIdx.x - 8192;
    const bf16* xr = x + (size_t)row * DMODEL;
    float s = 0.f;
    for (int i = tid; i < DMODEL; i += 256)
      s += __bfloat162float(xr[i]) * __bfloat162float(wg[i]);
#pragma unroll
    for (int m = 32; m; m >>= 1) s += __shfl_xor(s, m);
    if ((tid & 63) == 0) red[tid >> 6] = s;
    __syncthreads();
    if (tid == 0) {
      float tot = red[0] + red[1] + red[2] + red[3] + __bfloat162float(bg[0]);
      float a = 1.f / (1.f + expf(-tot));
      af[row] = a;
      size_t oi = (size_t)8388608 + row;   // alpha region of d_out
      if (*flag) ((float*)dout)[oi] = a;
      else       ((bf16*)dout)[oi] = __float2bfloat16(a);
    }
  }
}

// ---------------- fused flash attention: bidir + windowed-causal AR, one pass ----------------
// 512 threads / 8 waves, Q-tile 256 (32 rows/wave), K-tile 64, 32x32 MFMA,
// swapped operands (S^T = K·Q^T, O^T = V^T·P^T), lane-local softmax, P via
// pack+permlane32_swap. NATURAL K order (kb=0..2047): the 8 qt-blocks of a
// (b,h) pair sweep K/V in lockstep on ONE XCD (decode below) -> K/V served
// from that XCD's L2 (round-3-proven FETCH ~44 MB). AR via REGISTER snapshot
// (fits now: 512-thd block w/ launch_bounds(512,2) caps VGPR at 256;
// oacc 64 + snap 64 + qf 48 + staging 20 < 256 -> no spill, no arp buffer).
// Q-tile 256 doubles MFMA per staged byte / per barrier vs Q=128.
// Epilogue O^T->LDS transpose runs in two 4-wave phases (LDS reuse).
__global__ __launch_bounds__(512, 2) void attn_f(const bf16* __restrict__ qcr,
                                                 const bf16* __restrict__ kcv,
                                                 const bf16* __restrict__ xproj,
                                                 const bf16* __restrict__ vt,
                                                 const float* __restrict__ alphaF,
                                                 bf16* __restrict__ out) {
  constexpr int LDK = 200;  // 192 + pad
  constexpr int LDV = 72;   // 64 + pad
  __shared__ __align__(16) short sh[64 * LDK + 128 * LDV];  // 44032 B
  short* lk  = sh;
  short* lvt = sh + 64 * LDK;

  // XCD-pair-colocating decode (HW: XCD = flat % 8): pair p -> xcd p&7
  const int f_ = blockIdx.x;
  const int xcd = f_ & 7, g_ = f_ >> 3;
  const int qt = g_ & 7;
  const int p_ = xcd + 8 * (g_ >> 3);
  const int h = p_ & 15, b = p_ >> 4;

  const int qs = qt * 256;
  const int tid = threadIdx.x;
  const int w = tid >> 6, lane = tid & 63;
  const int l5 = lane & 31, h8 = lane >> 5;
  const int q0 = qs + w * 32;
  const int myq = q0 + l5;   // this lane's q row (S^T column)

  // Q fragments (B-operand: col=lane&31, k=(lane>>5)*8+v)
  v8bf qf[12];
  {
    const bf16* qcb = qcr + ((size_t)b * T_SEQ + myq) * 3072 + h * HDIM;
#pragma unroll
    for (int ks = 0; ks < 8; ks++)
      qf[ks] = *reinterpret_cast<const v8bf*>(qcb + ks * 16 + h8 * 8);
    const bf16* qrb = qcr + ((size_t)b * T_SEQ + myq) * 3072 + 2048 + h * RDIM;
#pragma unroll
    for (int ks = 0; ks < 4; ks++)
      qf[8 + ks] = *reinterpret_cast<const v8bf*>(qrb + ks * 16 + h8 * 8);
  }

  float l_sum = 0.f, l_snap = 0.f;
  f32x16 oacc[4], snap[4];
#pragma unroll
  for (int nd = 0; nd < 4; nd++)
#pragma unroll
    for (int r = 0; r < 16; r++) { oacc[nd][r] = 0.f; snap[nd][r] = 0.f; }

  const float a_q = alphaF[b * T_SEQ + myq];
  const float sc = 0.07216878364870323f;  // 1/sqrt(192)

  // AR window: this block IS one 256-chunk (CHUNK=256). klo 64-aligned.
  const int klo  = (qt > 0) ? (qs - 256) : 0;
  const int kb_d = qs + (w >> 1) * 64;    // wave's diagonal tile

  // staging (512 threads): K_c 1024 chunks (2/thd), k_r 512 (1/thd), V^T 1024 (2/thd)
  const int koc0 = (tid >> 4) * 4096 + (tid & 15) * 8;
  const int ldc0 = (tid >> 4) * LDK  + (tid & 15) * 8;
  const int kor0 = (tid >> 3) * 3072 + (tid & 7) * 8;
  const int ldr0 = (tid >> 3) * LDK + 128 + (tid & 7) * 8;
  const int kov0 = (tid >> 3) * 4096 + (tid & 7) * 8;
  const int ldv0 = (tid >> 3) * LDV  + (tid & 7) * 8;
  const bf16* kc_base = kcv   + (size_t)b * T_SEQ * 4096 + h * HDIM;
  const bf16* kr_base = xproj + (size_t)b * T_SEQ * 3072 + 2048 + h * RDIM;
  const bf16* v_base  = vt    + (size_t)h * HDIM * (2 * T_SEQ) + b * T_SEQ;

  v4u rc[2], rr1, rv[2];
  auto issue = [&](int kb) {
    const bf16* pc = kc_base + (size_t)kb * 4096;
    const bf16* pr = kr_base + (size_t)kb * 3072;
    const bf16* pv = v_base + kb;
#pragma unroll
    for (int i = 0; i < 2; i++) rc[i] = *reinterpret_cast<const v4u*>(pc + koc0 + i * 131072);
    rr1 = *reinterpret_cast<const v4u*>(pr + kor0);
#pragma unroll
    for (int i = 0; i < 2; i++) rv[i] = *reinterpret_cast<const v4u*>(pv + kov0 + i * 262144);
  };

  auto qk = [&](int j) -> f32x16 {
    f32x16 s;
#pragma unroll
    for (int r = 0; r < 16; r++) s[r] = 0.f;
#pragma unroll
    for (int ks = 0; ks < 12; ks++) {
      v8bf kf = *reinterpret_cast<const v8bf*>(&lk[(j * 32 + l5) * LDK + ks * 16 + h8 * 8]);
      s = __builtin_amdgcn_mfma_f32_32x32x16_bf16(kf, qf[ks], s, 0, 0, 0);
    }
    return s;
  };
  auto pack8 = [&](const float* p) -> v8bf {
    unsigned Y0 = pk2bf(p[0], p[1]);
    unsigned Y1 = pk2bf(p[2], p[3]);
    unsigned Y2 = pk2bf(p[4], p[5]);
    unsigned Y3 = pk2bf(p[6], p[7]);
    asm volatile("v_permlane32_swap_b32 %0, %1" : "+v"(Y0), "+v"(Y2));
    asm volatile("v_permlane32_swap_b32 %0, %1" : "+v"(Y1), "+v"(Y3));
    v4u t; t.x = Y0; t.y = Y1; t.z = Y2; t.w = Y3;
    return __builtin_bit_cast(v8bf, t);
  };
  auto pvj = [&](int j, const v8bf* pf) {
#pragma unroll
    for (int ck = 0; ck < 2; ck++)
#pragma unroll
      for (int nd = 0; nd < 4; nd++) {
        v8bf vf = *reinterpret_cast<const v8bf*>(&lvt[(nd * 32 + l5) * LDV + (j * 2 + ck) * 16 + h8 * 8]);
        oacc[nd] = __builtin_amdgcn_mfma_f32_32x32x16_bf16(vf, pf[ck], oacc[nd], 0, 0, 0);
      }
  };
  auto plainpass = [&](int j) {
    f32x16 s = qk(j);
    v8bf pf[2];
#pragma unroll
    for (int cc = 0; cc < 2; cc++) {
      float p[8];
#pragma unroll
      for (int r8 = 0; r8 < 8; r8++) {
        float e = __expf(s[cc * 8 + r8] * sc);
        p[r8] = e;
        l_sum += e;
      }
      pf[cc] = pack8(p);
    }
    pvj(j, pf);
  };
  auto maskpass = [&](int j, int kb, bool upper) {
    f32x16 s = qk(j);
    v8bf pf[2];
#pragma unroll
    for (int cc = 0; cc < 2; cc++) {
      float p[8];
#pragma unroll
      for (int r8 = 0; r8 < 8; r8++) {
        int r = cc * 8 + r8;
        int kk = kb + j * 32 + (r & 3) + 8 * (r >> 2) + 4 * h8;
        float e = __expf(s[r] * sc);
        bool keep = upper ? (kk > myq) : (kk <= myq);
        e = keep ? e : 0.f;
        p[r8] = e;
        l_sum += e;
      }
      pf[cc] = pack8(p);
    }
    pvj(j, pf);
  };

  issue(0);

  for (int kb = 0; kb < T_SEQ; kb += 64) {
    __syncthreads();  // WAR: all waves done reading previous tile
    // commit prefetched tile to LDS (compiler inserts vmcnt waits)
#pragma unroll
    for (int i = 0; i < 2; i++) *reinterpret_cast<v4u*>(&lk[ldc0 + i * 32 * LDK]) = rc[i];
    *reinterpret_cast<v4u*>(&lk[ldr0]) = rr1;
#pragma unroll
    for (int i = 0; i < 2; i++) *reinterpret_cast<v4u*>(&lvt[ldv0 + i * 64 * LDV]) = rv[i];
    if (kb + 64 < T_SEQ) issue(kb + 64);  // loads stay in flight across compute
    __syncthreads();

    if (kb == klo) {  // snapshot pre-window state (wave-uniform branch)
#pragma unroll
      for (int nd = 0; nd < 4; nd++) snap[nd] = oacc[nd];
      l_snap = l_sum;
    }

    __builtin_amdgcn_s_setprio(1);
    if (kb != kb_d) {
      plainpass(0);
      plainpass(1);
    } else {
      // diagonal tile: lower-masked completes AR; extract AR into snap; complement
      maskpass(0, kb, false);
      maskpass(1, kb, false);
      {
        float lar_h = l_sum - l_snap;
        float lar = lar_h + __shfl_xor(lar_h, 32);
        float sAR = (1.f - a_q) / lar;
#pragma unroll
        for (int nd = 0; nd < 4; nd++)
#pragma unroll
          for (int r = 0; r < 16; r++)
            snap[nd][r] = (oacc[nd][r] - snap[nd][r]) * sAR;
      }
      maskpass(0, kb, true);
      maskpass(1, kb, true);
    }
    __builtin_amdgcn_s_setprio(0);
  }

  // combine softmax denominator across lane halves
  l_sum += __shfl_xor(l_sum, 32);
  float inv = a_q / l_sum;

  // epilogue: merged = a·O_b/l_b + (1-a)·O_ar/l_ar (all regs);
  // O^T -> LDS -> coalesced store, in two 4-wave phases (LDS capacity)
  __syncthreads();  // all waves done with lk/lvt
#pragma unroll
  for (int ph = 0; ph < 2; ph++) {
    bool act = (w >> 2) == ph;
    short* tile = sh + (w & 3) * (32 * 136);
    if (act) {
#pragma unroll
      for (int nd = 0; nd < 4; nd++)
#pragma unroll
        for (int rg = 0; rg < 4; rg++) {
          v4s pk;
#pragma unroll
          for (int i = 0; i < 4; i++) {
            float val = oacc[nd][rg * 4 + i] * inv + snap[nd][rg * 4 + i];
            pk[i] = f2bfbits(val);
          }
          // d = nd*32 + rg*8 + h8*4 + i  (C/D row formula), q = l5
          *reinterpret_cast<v4s*>(&tile[l5 * 136 + nd * 32 + rg * 8 + h8 * 4]) = pk;
        }
    }
    __syncthreads();
    if (act) {
#pragma unroll
      for (int i = 0; i < 8; i++) {
        int r = i * 4 + (lane >> 4);
        int q2 = q0 + r;
        int dcol = (lane & 15) * 8;
        v8s mv = *reinterpret_cast<const v8s*>(&tile[r * 136 + dcol]);
        size_t gbase = ((size_t)b * T_SEQ + q2) * DMODEL + h * HDIM + dcol;
        *reinterpret_cast<v8s*>((void*)(out + gbase)) = mv;
      }
    }
    __syncthreads();
  }
}

extern "C" void kernel_launch(void* const* d_in, const int* in_sizes, int n_in,
                              void* d_out, int out_size, void* d_ws, size_t ws_size,
                              hipStream_t stream) {
  const void* x_raw    = d_in[0];
  const void* unc_raw  = d_in[1];
  const void* Wqd_raw  = d_in[2];
  const void* qnw_raw  = d_in[3];
  const void* Wqu_raw  = d_in[4];
  const void* Wqr_raw  = d_in[5];
  const void* Wkvd_raw = d_in[6];
  const void* kvnw_raw = d_in[7];
  const void* Wku_raw  = d_in[8];
  const void* Wvu_raw  = d_in[9];
  const void* Wkr_raw  = d_in[10];
  const void* Wo_raw   = d_in[11];
  const void* Wg_raw   = d_in[12];
  const void* bg_raw   = d_in[13];

  char* ws = (char*)d_ws;
  size_t off = 0;
  auto alloc = [&](size_t bytes) -> void* {
    char* p = ws + off;
    off += (bytes + 255) & ~(size_t)255;
    return p;
  };
  int*  flag   = (int*)alloc(256);
  bf16* xc     = (bf16*)alloc((size_t)4096 * 2048 * 2);
  float* uncf  = (float*)alloc((size_t)4096 * 4);
  bf16* qnw    = (bf16*)alloc(1536 * 2);
  bf16* kvnw   = (bf16*)alloc(512 * 2);
  bf16* wgc    = (bf16*)alloc(2048 * 2);
  bf16* bgc    = (bf16*)alloc(256);
  bf16* BT1    = (bf16*)alloc((size_t)3072 * 2048 * 2);  // [WqdT;WkvdT;WkrT], K=2048
  bf16* BT2    = (bf16*)alloc((size_t)3072 * 1536 * 2);  // [WquT;WqrT], K=1536
  bf16* BT3    = (bf16*)alloc((size_t)4096 * 512 * 2);   // [WkuT;WvuT], K=512
  bf16* WoT    = (bf16*)alloc((size_t)2048 * 2048 * 2);
  bf16* xproj  = (bf16*)alloc((size_t)4096 * 3072 * 2);  // [q_raw|kv_raw|k_r]
  bf16* q_lat  = (bf16*)alloc((size_t)4096 * 1536 * 2);
  bf16* kv_lat = (bf16*)alloc((size_t)4096 * 512 * 2);
  bf16* qcr    = (bf16*)alloc((size_t)4096 * 3072 * 2);  // [q_c|q_r]
  bf16* kcv    = (bf16*)alloc((size_t)4096 * 4096 * 2);  // [k_c|v]
  bf16* vT     = (bf16*)alloc((size_t)4096 * 2048 * 2);
  bf16* attno  = (bf16*)alloc((size_t)4096 * 2048 * 2);  // merged attention out
  float* alphaF= (float*)alloc((size_t)4096 * 4);

  detect_k<<<1, 256, 0, stream>>>((const unsigned*)x_raw, flag);

  conv_all<<<8225, 256, 0, stream>>>(x_raw, qnw_raw, kvnw_raw, Wg_raw, bg_raw, unc_raw,
                                     xc, qnw, kvnw, wgc, bgc, uncf, flag);

  // one dispatch for all 8 weight transposes
  TP8 jobs;
  const void* srcs[8] = {Wqd_raw, Wkvd_raw, Wkr_raw, Wqu_raw, Wqr_raw, Wku_raw, Wvu_raw, Wo_raw};
  bf16* dsts[8] = {BT1, BT1 + (size_t)1536 * 2048, BT1 + (size_t)2048 * 2048,
                   BT2, BT2 + (size_t)2048 * 1536,
                   BT3, BT3 + (size_t)2048 * 512, WoT};
  int rws[8] = {2048, 2048, 2048, 1536, 1536, 512, 512, 2048};
  int cls[8] = {1536, 512, 1024, 2048, 1024, 2048, 2048, 2048};
  int acc_t = 0;
  for (int i = 0; i < 8; i++) {
    jobs.s[i] = srcs[i]; jobs.d[i] = dsts[i];
    jobs.rows[i] = rws[i]; jobs.cols[i] = cls[i];
    jobs.pre[i] = acc_t;
    acc_t += (rws[i] / 32) * (cls[i] / 32);
  }
  jobs.pre[8] = acc_t;
  transpose_all<<<acc_t, 256, 0, stream>>>(jobs, flag);

  auto gemmb = [&](const bf16* A, const bf16* BT, bf16* C, int M, int N, int K) {
    gemm_tn<<<dim3(N / 128, M / 128), 256, 0, stream>>>(A, BT, C, M, N, K, nullptr, nullptr);
  };

  gemmb(xc, BT1, xproj, 4096, 3072, 2048);                 // [q_raw|kv_raw|k_r]
  rmsnorm_both<<<8192, 256, 0, stream>>>(xproj, qnw, kvnw, q_lat, kv_lat);
  gemmb(q_lat, BT2, qcr, 4096, 3072, 1536);                // [q_c|q_r]
  gemmb(kv_lat, BT3, kcv, 4096, 4096, 512);                // [k_c|v]

  // V^T: vT[d][b*T+t] from kcv cols 2048..4095
  transpose_str<<<dim3(64, 128), 256, 0, stream>>>(kcv + 2048, vT, 4096, 4096);

  rope_gate<<<12288, 256, 0, stream>>>(qcr, xproj, uncf, xc, wgc, bgc, alphaF, d_out, flag);

  // single fused attention (bidir + AR + alpha-merge), Q-tile 256, 8 waves,
  // XCD-pair-colocated flat grid (256 blocks = 8 qt x 32 pairs)
  attn_f<<<256, 512, 0, stream>>>(qcr, kcv, xproj, vT, alphaF, attno);

  // final projection writes d_out directly in detected dtype
  gemm_tn<<<dim3(16, 32), 256, 0, stream>>>(attno, WoT, nullptr, 4096, 2048, 2048, flag, d_out);

  (void)in_sizes; (void)n_in; (void)out_size; (void)ws_size;
}

// Round 7
// 606.414 us; speedup vs baseline: 1.3408x; 1.0569x over previous
//
#include <hip/hip_runtime.h>
#include <hip/hip_bf16.h>
#include <math.h>

typedef __hip_bfloat16 bf16;
using v8bf = __attribute__((ext_vector_type(8))) __bf16;
using v4f  = __attribute__((ext_vector_type(4))) float;
using f32x16 = __attribute__((ext_vector_type(16))) float;
using v4u = __attribute__((ext_vector_type(4))) unsigned;
using v4s = __attribute__((ext_vector_type(4))) short;
using v8s = __attribute__((ext_vector_type(8))) short;

#define T_SEQ 2048
#define DMODEL 2048
#define NHEADS 16
#define HDIM 128
#define RDIM 64

__device__ __forceinline__ short f2bfbits(float f) {
  bf16 h = __float2bfloat16(f);
  short s;
  __builtin_memcpy(&s, &h, 2);
  return s;
}

__device__ __forceinline__ unsigned pk2bf(float a, float b) {
  unsigned lo = (unsigned short)f2bfbits(a);
  unsigned hi = (unsigned short)f2bfbits(b);
  return lo | (hi << 16);
}

// async global->LDS, 16B per lane
typedef const __attribute__((address_space(1))) unsigned gu32;
typedef __attribute__((address_space(3))) unsigned lu32;
__device__ __forceinline__ void gl_lds16(const void* g, void* l) {
  __builtin_amdgcn_global_load_lds((gu32*)g, (lu32*)l, 16, 0, 0);
}

template <int N>
__device__ __forceinline__ void vwn() {
  asm volatile("s_waitcnt vmcnt(%0)" :: "n"(N) : "memory");
}

// ---------------- dtype detection ----------------
__global__ void detect_k(const unsigned* __restrict__ x, int* __restrict__ flag) {
  __shared__ int cnt;
  if (threadIdx.x == 0) cnt = 0;
  __syncthreads();
  int c = 0;
#pragma unroll
  for (int i = 0; i < 4; i++) {
    unsigned w = x[threadIdx.x * 4 + i];
    unsigned e = (w >> 7) & 0xFFu;
    if (e < 97u || e > 157u) c++;
  }
  atomicAdd(&cnt, c);
  __syncthreads();
  if (threadIdx.x == 0) flag[0] = (cnt > 256) ? 1 : 0;  // 1 = f32 inputs
}

// ---------------- fused canonicalize: x (vectorized x4) + all small inputs ----------------
__global__ __launch_bounds__(256) void conv_all(const void* x_raw,
                                                const void* qnw_raw, const void* kvnw_raw,
                                                const void* wg_raw, const void* bg_raw,
                                                const void* unc_raw,
                                                bf16* xc, bf16* qnw, bf16* kvnw,
                                                bf16* wgc, bf16* bgc, float* uncf,
                                                const int* flag) {
  bool isf = (*flag != 0);
  if (blockIdx.x < 8192) {
    int i4 = blockIdx.x * 256 + threadIdx.x;   // vector index (4 elems each)
    v4s o;
    if (isf) {
      float4 v = ((const float4*)x_raw)[i4];
      o[0] = f2bfbits(v.x); o[1] = f2bfbits(v.y);
      o[2] = f2bfbits(v.z); o[3] = f2bfbits(v.w);
    } else {
      o = ((const v4s*)x_raw)[i4];
    }
    *reinterpret_cast<v4s*>(xc + (size_t)i4 * 4) = o;
  } else {
    int i = (blockIdx.x - 8192) * 256 + threadIdx.x;
    if (i < 1536) qnw[i] = isf ? __float2bfloat16(((const float*)qnw_raw)[i]) : ((const bf16*)qnw_raw)[i];
    else if (i < 2048) { int j = i - 1536; kvnw[j] = isf ? __float2bfloat16(((const float*)kvnw_raw)[j]) : ((const bf16*)kvnw_raw)[j]; }
    else if (i < 4096) { int j = i - 2048; wgc[j] = isf ? __float2bfloat16(((const float*)wg_raw)[j]) : ((const bf16*)wg_raw)[j]; }
    else if (i < 4097) bgc[0] = isf ? __float2bfloat16(((const float*)bg_raw)[0]) : ((const bf16*)bg_raw)[0];
    else if (i < 8193) { int j = i - 4097; uncf[j] = isf ? ((const float*)unc_raw)[j] : __bfloat162float(((const bf16*)unc_raw)[j]); }
  }
}

// ---------------- all 8 weight transposes in one dispatch ----------------
struct TP8 {
  const void* s[8];
  bf16* d[8];
  int rows[8];
  int cols[8];
  int pre[9];
};

__global__ __launch_bounds__(256) void transpose_all(TP8 jobs, const int* __restrict__ flag) {
  __shared__ bf16 tile[32][33];
  int bid = blockIdx.x;
  int w = 0;
#pragma unroll
  for (int k = 0; k < 7; k++) if (bid >= jobs.pre[k + 1]) w = k + 1;
  int lt = bid - jobs.pre[w];
  int rows = jobs.rows[w], cols = jobs.cols[w];
  int tpr = cols >> 5;
  int by = (lt / tpr) << 5, bx = (lt % tpr) << 5;
  const void* src = jobs.s[w];
  bf16* dst = jobs.d[w];
  int tx = threadIdx.x & 31, ty = threadIdx.x >> 5;
  bool isf = (*flag != 0);
#pragma unroll
  for (int i = 0; i < 32; i += 8) {
    size_t idx = (size_t)(by + ty + i) * cols + bx + tx;
    tile[ty + i][tx] = isf ? __float2bfloat16(((const float*)src)[idx])
                           : ((const bf16*)src)[idx];
  }
  __syncthreads();
#pragma unroll
  for (int i = 0; i < 32; i += 8)
    dst[(size_t)(bx + ty + i) * rows + by + tx] = tile[tx][ty + i];
}

// ---------------- strided bf16 transpose (V^T out of fused kcv) ----------------
__global__ __launch_bounds__(256) void transpose_str(const bf16* __restrict__ src,
                                                     bf16* __restrict__ dst,
                                                     int srcStride, int dstStride) {
  __shared__ bf16 tile[32][33];
  int bx = blockIdx.x * 32, by = blockIdx.y * 32;
  int tx = threadIdx.x & 31, ty = threadIdx.x >> 5;
#pragma unroll
  for (int i = 0; i < 32; i += 8)
    tile[ty + i][tx] = src[(size_t)(by + ty + i) * srcStride + bx + tx];
  __syncthreads();
#pragma unroll
  for (int i = 0; i < 32; i += 8)
    dst[(size_t)(bx + ty + i) * dstStride + by + tx] = tile[tx][ty + i];
}

// ---------------- 8-phase 256x256 TN GEMM: C[M,N] = A[M,K] * BT[N,K]^T ----------------
// 512 threads / 8 waves, BK=64, LDS 128 KiB double-buffered (A/B x 2 halves each).
// Phase p (0..3 per K-tile) computes C-quadrant (p>>1, p&1): all 8 waves on one
// 128x128 quadrant -> each phase reads ONE A-half + ONE B-half. Stage order for
// next tile: A0,B0,B1,A1, one half per phase (2 gl_lds/wave). Counted vmcnt(4)
// at phases 0,1,3 (never 0): each half drains exactly before its first read;
// 4-8 loads stay in flight across barriers (T3+T4). T2-lite swizzle:
// col ^= (row&12)<<3 on BOTH gl_lds global source and ds_read addr (16->4-way).
__global__ __launch_bounds__(512, 2) void gemm8(const bf16* __restrict__ A,
                                                const bf16* __restrict__ BT,
                                                bf16* __restrict__ Cb,
                                                int M, int N, int K,
                                                const int* __restrict__ oflag,
                                                void* __restrict__ dvout) {
  __shared__ __align__(16) short lds[2][2][16384];  // [buf][0=A,1=B][256*64]
  const int m0 = blockIdx.y * 256, n0 = blockIdx.x * 256;
  const int tid = threadIdx.x;
  const int w = tid >> 6, lane = tid & 63;
  const int quad4 = lane >> 4, l16 = lane & 15;
  const int wmq = (w >> 1) * 32;   // wave M-offset within quadrant (4 waves x 32)
  const int wnq = (w & 1) * 64;    // wave N-offset within quadrant (2 waves x 64)

  v4f acc[4][2][4];
#pragma unroll
  for (int qi = 0; qi < 4; qi++)
#pragma unroll
    for (int mf = 0; mf < 2; mf++)
#pragma unroll
      for (int nf = 0; nf < 4; nf++) acc[qi][mf][nf] = (v4f){0.f, 0.f, 0.f, 0.f};

  // stage one half-tile (sp: 0=A0,1=B0,2=B1,3=A1) of K-tile at kb into buf sbuf
  auto stage_half = [&](int sp, int kb, int sbuf) {
    const int mat = (sp == 0 || sp == 3) ? 0 : 1;
    const int half = (sp >= 2) ? 1 : 0;
    const bf16* base = mat ? BT : A;
    const int rbase = (mat ? n0 : m0) + half * 128 + w * 16;
#pragma unroll
    for (int i = 0; i < 2; i++) {
      int lrow = half * 128 + w * 16 + i * 8;          // LDS row (wave-uniform)
      short* dst = &lds[sbuf][mat][lrow * 64];
      int rl = i * 8 + (lane >> 3);                    // row bits for swizzle
      int grow = rbase + i * 8 + (lane >> 3);
      int cb = ((lane & 7) * 16) ^ ((rl & 12) << 3);   // pre-swizzled col byte
      const bf16* src = base + (size_t)grow * K + kb + (cb >> 1);
      gl_lds16(src, dst);
    }
  };

#define GEMM8_PHASE(BUF, PH, STAGE_STMT, WAIT_STMT) do {                          \
    constexpr int qm_ = (PH) >> 1, qn_ = (PH) & 1;                                \
    v8bf a_[2][2], b_[2][4];                                                      \
    _Pragma("unroll")                                                             \
    for (int ks = 0; ks < 2; ks++) {                                              \
      _Pragma("unroll")                                                           \
      for (int mf = 0; mf < 2; mf++) {                                            \
        int r_ = qm_ * 128 + wmq + mf * 16 + l16;                                 \
        int c_ = (ks * 64 + quad4 * 16) ^ ((r_ & 12) << 3);                       \
        a_[ks][mf] = *reinterpret_cast<const v8bf*>(                              \
            (const char*)&lds[BUF][0][0] + r_ * 128 + c_);                        \
      }                                                                           \
      _Pragma("unroll")                                                           \
      for (int nf = 0; nf < 4; nf++) {                                            \
        int r_ = qn_ * 128 + wnq + nf * 16 + l16;                                 \
        int c_ = (ks * 64 + quad4 * 16) ^ ((r_ & 12) << 3);                       \
        b_[ks][nf] = *reinterpret_cast<const v8bf*>(                              \
            (const char*)&lds[BUF][1][0] + r_ * 128 + c_);                        \
      }                                                                           \
    }                                                                             \
    STAGE_STMT;                                                                   \
    WAIT_STMT;                                                                    \
    __builtin_amdgcn_s_barrier();                                                 \
    __builtin_amdgcn_s_setprio(1);                                                \
    _Pragma("unroll")                                                             \
    for (int ks = 0; ks < 2; ks++)                                                \
      _Pragma("unroll")                                                           \
      for (int mf = 0; mf < 2; mf++)                                              \
        _Pragma("unroll")                                                         \
        for (int nf = 0; nf < 4; nf++)                                            \
          acc[qm_ * 2 + qn_][mf][nf] = __builtin_amdgcn_mfma_f32_16x16x32_bf16(   \
              a_[ks][mf], b_[ks][nf], acc[qm_ * 2 + qn_][mf][nf], 0, 0, 0);       \
    __builtin_amdgcn_s_setprio(0);                                                \
    __builtin_amdgcn_s_barrier();                                                 \
  } while (0)

  const int T = K >> 6;  // K-tiles (K % 128 == 0, T >= 2)

  // prologue: stage tile0 -> buf0, tile1 -> buf1 (8 loads each per wave pattern)
#pragma unroll
  for (int sp = 0; sp < 4; sp++) stage_half(sp, 0, 0);
#pragma unroll
  for (int sp = 0; sp < 4; sp++) stage_half(sp, 64, 1);
  vwn<12>();                    // tile0 A0,B0 arrived
  __builtin_amdgcn_s_barrier();

  // tile 0 (buf 0), no staging; drain tile0 B1 / A1 / tile1 A0,B0
  GEMM8_PHASE(0, 0, (void)0, vwn<10>());
  GEMM8_PHASE(0, 1, (void)0, vwn<8>());
  GEMM8_PHASE(0, 2, (void)0, (void)0);
  GEMM8_PHASE(0, 3, (void)0, vwn<4>());

  // middle tiles: compute buf t&1, stage tile t+1 into the other buffer
  for (int t = 1; t <= T - 2; t++) {
    const int buf = t & 1, sbuf = buf ^ 1, kbn = (t + 1) << 6;
    GEMM8_PHASE(buf, 0, stage_half(0, kbn, sbuf), vwn<4>());
    GEMM8_PHASE(buf, 1, stage_half(1, kbn, sbuf), vwn<4>());
    GEMM8_PHASE(buf, 2, stage_half(2, kbn, sbuf), (void)0);
    GEMM8_PHASE(buf, 3, stage_half(3, kbn, sbuf), vwn<4>());
  }

  // last tile, no staging; drain its B1 then A1
  {
    const int buf = (T - 1) & 1;
    GEMM8_PHASE(buf, 0, (void)0, vwn<2>());
    GEMM8_PHASE(buf, 1, (void)0, vwn<0>());
    GEMM8_PHASE(buf, 2, (void)0, (void)0);
    GEMM8_PHASE(buf, 3, (void)0, (void)0);
  }
#undef GEMM8_PHASE

  // epilogue: C write (C/D layout: col=lane&15, row=(lane>>4)*4+r)
  const bool isf = dvout && (*oflag != 0);
#pragma unroll
  for (int qi = 0; qi < 4; qi++) {
    const int qm = qi >> 1, qn = qi & 1;
#pragma unroll
    for (int mf = 0; mf < 2; mf++)
#pragma unroll
      for (int nf = 0; nf < 4; nf++)
#pragma unroll
        for (int r = 0; r < 4; r++) {
          int row = m0 + qm * 128 + wmq + mf * 16 + quad4 * 4 + r;
          int col = n0 + qn * 128 + wnq + nf * 16 + l16;
          float vv = acc[qi][mf][nf][r];
          size_t idx = (size_t)row * N + col;
          if (dvout) {
            if (isf) ((float*)dvout)[idx] = vv;
            else     ((bf16*)dvout)[idx] = __float2bfloat16(vv);
          } else {
            Cb[idx] = __float2bfloat16(vv);
          }
        }
  }
}

// ---------------- both RMS norms in one dispatch ----------------
__global__ __launch_bounds__(256) void rmsnorm_both(const bf16* __restrict__ xproj,
                                                    const bf16* __restrict__ qnw,
                                                    const bf16* __restrict__ kvnw,
                                                    bf16* __restrict__ q_lat,
                                                    bf16* __restrict__ kv_lat) {
  int bid = blockIdx.x, tid = threadIdx.x;
  bool isq = bid < 4096;
  int row = isq ? bid : bid - 4096;
  int C = isq ? 1536 : 512;
  const bf16* r = xproj + (size_t)row * 3072 + (isq ? 0 : 1536);
  const bf16* w = isq ? qnw : kvnw;
  bf16* o = (isq ? q_lat : kv_lat) + (size_t)row * C;
  float s = 0.f;
  for (int i = tid; i < C; i += 256) { float v = __bfloat162float(r[i]); s += v * v; }
#pragma unroll
  for (int m = 32; m; m >>= 1) s += __shfl_xor(s, m);
  __shared__ float red[4];
  if ((tid & 63) == 0) red[tid >> 6] = s;
  __syncthreads();
  float tot = red[0] + red[1] + red[2] + red[3];
  float rs = rsqrtf(tot / (float)C + 1e-6f);
  for (int i = tid; i < C; i += 256)
    o[i] = __float2bfloat16(__bfloat162float(r[i]) * rs * __bfloat162float(w[i]));
}

// ---------------- rope (q_r in qcr, k_r in xproj) + gate (writes d_out alpha) ----------------
__global__ __launch_bounds__(256) void rope_gate(bf16* __restrict__ qcr,
                                                 bf16* __restrict__ xproj,
                                                 const float* __restrict__ unc,
                                                 const bf16* __restrict__ x,
                                                 const bf16* __restrict__ wg,
                                                 const bf16* __restrict__ bg,
                                                 float* __restrict__ af,
                                                 void* __restrict__ dout,
                                                 const int* __restrict__ flag) {
  __shared__ float red[4];
  int tid = threadIdx.x;
  if (blockIdx.x < 8192) {
    int idx = blockIdx.x * 256 + tid;
    int j = idx & 31, h = (idx >> 5) & 15, bt = idx >> 9;
    int t = bt & (T_SEQ - 1);
    float u = unc[bt];
    u = fminf(fmaxf(u, 0.f), 1.f);
    float scale = 0.5f + 1.5f * u;
    float theta = expf(-(float)j * (1.f / 32.f) * logf(500000.f));
    float f = (float)t * theta * scale;
    float c = cosf(f), s = sinf(f);
    size_t base = (size_t)bt * 3072 + 2048 + h * RDIM + j;
    {
      float x1 = __bfloat162float(qcr[base]), x2 = __bfloat162float(qcr[base + 32]);
      qcr[base]      = __float2bfloat16(x1 * c - x2 * s);
      qcr[base + 32] = __float2bfloat16(x2 * c + x1 * s);
    }
    {
      float x1 = __bfloat162float(xproj[base]), x2 = __bfloat162float(xproj[base + 32]);
      xproj[base]      = __float2bfloat16(x1 * c - x2 * s);
      xproj[base + 32] = __float2bfloat16(x2 * c + x1 * s);
    }
  } else {
    int row = blockIdx.x - 8192;
    const bf16* xr = x + (size_t)row * DMODEL;
    float s = 0.f;
    for (int i = tid; i < DMODEL; i += 256)
      s += __bfloat162float(xr[i]) * __bfloat162float(wg[i]);
#pragma unroll
    for (int m = 32; m; m >>= 1) s += __shfl_xor(s, m);
    if ((tid & 63) == 0) red[tid >> 6] = s;
    __syncthreads();
    if (tid == 0) {
      float tot = red[0] + red[1] + red[2] + red[3] + __bfloat162float(bg[0]);
      float a = 1.f / (1.f + expf(-tot));
      af[row] = a;
      size_t oi = (size_t)8388608 + row;   // alpha region of d_out
      if (*flag) ((float*)dout)[oi] = a;
      else       ((bf16*)dout)[oi] = __float2bfloat16(a);
    }
  }
}

// ---------------- fused flash attention: bidir + windowed-causal AR, one pass ----------------
// (round-6 proven: 512 thr / 8 waves, Q-tile 256, register AR snapshot,
//  natural K order + XCD-pair colocation -> FETCH ~39 MB)
__global__ __launch_bounds__(512, 2) void attn_f(const bf16* __restrict__ qcr,
                                                 const bf16* __restrict__ kcv,
                                                 const bf16* __restrict__ xproj,
                                                 const bf16* __restrict__ vt,
                                                 const float* __restrict__ alphaF,
                                                 bf16* __restrict__ out) {
  constexpr int LDK = 200;  // 192 + pad
  constexpr int LDV = 72;   // 64 + pad
  __shared__ __align__(16) short sh[64 * LDK + 128 * LDV];  // 44032 B
  short* lk  = sh;
  short* lvt = sh + 64 * LDK;

  // XCD-pair-colocating decode (HW: XCD = flat % 8): pair p -> xcd p&7
  const int f_ = blockIdx.x;
  const int xcd = f_ & 7, g_ = f_ >> 3;
  const int qt = g_ & 7;
  const int p_ = xcd + 8 * (g_ >> 3);
  const int h = p_ & 15, b = p_ >> 4;

  const int qs = qt * 256;
  const int tid = threadIdx.x;
  const int w = tid >> 6, lane = tid & 63;
  const int l5 = lane & 31, h8 = lane >> 5;
  const int q0 = qs + w * 32;
  const int myq = q0 + l5;   // this lane's q row (S^T column)

  // Q fragments (B-operand: col=lane&31, k=(lane>>5)*8+v)
  v8bf qf[12];
  {
    const bf16* qcb = qcr + ((size_t)b * T_SEQ + myq) * 3072 + h * HDIM;
#pragma unroll
    for (int ks = 0; ks < 8; ks++)
      qf[ks] = *reinterpret_cast<const v8bf*>(qcb + ks * 16 + h8 * 8);
    const bf16* qrb = qcr + ((size_t)b * T_SEQ + myq) * 3072 + 2048 + h * RDIM;
#pragma unroll
    for (int ks = 0; ks < 4; ks++)
      qf[8 + ks] = *reinterpret_cast<const v8bf*>(qrb + ks * 16 + h8 * 8);
  }

  float l_sum = 0.f, l_snap = 0.f;
  f32x16 oacc[4], snap[4];
#pragma unroll
  for (int nd = 0; nd < 4; nd++)
#pragma unroll
    for (int r = 0; r < 16; r++) { oacc[nd][r] = 0.f; snap[nd][r] = 0.f; }

  const float a_q = alphaF[b * T_SEQ + myq];
  const float sc = 0.07216878364870323f;  // 1/sqrt(192)

  // AR window: this block IS one 256-chunk (CHUNK=256). klo 64-aligned.
  const int klo  = (qt > 0) ? (qs - 256) : 0;
  const int kb_d = qs + (w >> 1) * 64;    // wave's diagonal tile

  // staging (512 threads): K_c 1024 chunks (2/thd), k_r 512 (1/thd), V^T 1024 (2/thd)
  const int koc0 = (tid >> 4) * 4096 + (tid & 15) * 8;
  const int ldc0 = (tid >> 4) * LDK  + (tid & 15) * 8;
  const int kor0 = (tid >> 3) * 3072 + (tid & 7) * 8;
  const int ldr0 = (tid >> 3) * LDK + 128 + (tid & 7) * 8;
  const int kov0 = (tid >> 3) * 4096 + (tid & 7) * 8;
  const int ldv0 = (tid >> 3) * LDV  + (tid & 7) * 8;
  const bf16* kc_base = kcv   + (size_t)b * T_SEQ * 4096 + h * HDIM;
  const bf16* kr_base = xproj + (size_t)b * T_SEQ * 3072 + 2048 + h * RDIM;
  const bf16* v_base  = vt    + (size_t)h * HDIM * (2 * T_SEQ) + b * T_SEQ;

  v4u rc[2], rr1, rv[2];
  auto issue = [&](int kb) {
    const bf16* pc = kc_base + (size_t)kb * 4096;
    const bf16* pr = kr_base + (size_t)kb * 3072;
    const bf16* pv = v_base + kb;
#pragma unroll
    for (int i = 0; i < 2; i++) rc[i] = *reinterpret_cast<const v4u*>(pc + koc0 + i * 131072);
    rr1 = *reinterpret_cast<const v4u*>(pr + kor0);
#pragma unroll
    for (int i = 0; i < 2; i++) rv[i] = *reinterpret_cast<const v4u*>(pv + kov0 + i * 262144);
  };

  auto qk = [&](int j) -> f32x16 {
    f32x16 s;
#pragma unroll
    for (int r = 0; r < 16; r++) s[r] = 0.f;
#pragma unroll
    for (int ks = 0; ks < 12; ks++) {
      v8bf kf = *reinterpret_cast<const v8bf*>(&lk[(j * 32 + l5) * LDK + ks * 16 + h8 * 8]);
      s = __builtin_amdgcn_mfma_f32_32x32x16_bf16(kf, qf[ks], s, 0, 0, 0);
    }
    return s;
  };
  auto pack8 = [&](const float* p) -> v8bf {
    unsigned Y0 = pk2bf(p[0], p[1]);
    unsigned Y1 = pk2bf(p[2], p[3]);
    unsigned Y2 = pk2bf(p[4], p[5]);
    unsigned Y3 = pk2bf(p[6], p[7]);
    asm volatile("v_permlane32_swap_b32 %0, %1" : "+v"(Y0), "+v"(Y2));
    asm volatile("v_permlane32_swap_b32 %0, %1" : "+v"(Y1), "+v"(Y3));
    v4u t; t.x = Y0; t.y = Y1; t.z = Y2; t.w = Y3;
    return __builtin_bit_cast(v8bf, t);
  };
  auto pvj = [&](int j, const v8bf* pf) {
#pragma unroll
    for (int ck = 0; ck < 2; ck++)
#pragma unroll
      for (int nd = 0; nd < 4; nd++) {
        v8bf vf = *reinterpret_cast<const v8bf*>(&lvt[(nd * 32 + l5) * LDV + (j * 2 + ck) * 16 + h8 * 8]);
        oacc[nd] = __builtin_amdgcn_mfma_f32_32x32x16_bf16(vf, pf[ck], oacc[nd], 0, 0, 0);
      }
  };
  auto plainpass = [&](int j) {
    f32x16 s = qk(j);
    v8bf pf[2];
#pragma unroll
    for (int cc = 0; cc < 2; cc++) {
      float p[8];
#pragma unroll
      for (int r8 = 0; r8 < 8; r8++) {
        float e = __expf(s[cc * 8 + r8] * sc);
        p[r8] = e;
        l_sum += e;
      }
      pf[cc] = pack8(p);
    }
    pvj(j, pf);
  };
  auto maskpass = [&](int j, int kb, bool upper) {
    f32x16 s = qk(j);
    v8bf pf[2];
#pragma unroll
    for (int cc = 0; cc < 2; cc++) {
      float p[8];
#pragma unroll
      for (int r8 = 0; r8 < 8; r8++) {
        int r = cc * 8 + r8;
        int kk = kb + j * 32 + (r & 3) + 8 * (r >> 2) + 4 * h8;
        float e = __expf(s[r] * sc);
        bool keep = upper ? (kk > myq) : (kk <= myq);
        e = keep ? e : 0.f;
        p[r8] = e;
        l_sum += e;
      }
      pf[cc] = pack8(p);
    }
    pvj(j, pf);
  };

  issue(0);

  for (int kb = 0; kb < T_SEQ; kb += 64) {
    __syncthreads();  // WAR: all waves done reading previous tile
    // commit prefetched tile to LDS (compiler inserts vmcnt waits)
#pragma unroll
    for (int i = 0; i < 2; i++) *reinterpret_cast<v4u*>(&lk[ldc0 + i * 32 * LDK]) = rc[i];
    *reinterpret_cast<v4u*>(&lk[ldr0]) = rr1;
#pragma unroll
    for (int i = 0; i < 2; i++) *reinterpret_cast<v4u*>(&lvt[ldv0 + i * 64 * LDV]) = rv[i];
    if (kb + 64 < T_SEQ) issue(kb + 64);  // loads stay in flight across compute
    __syncthreads();

    if (kb == klo) {  // snapshot pre-window state (wave-uniform branch)
#pragma unroll
      for (int nd = 0; nd < 4; nd++) snap[nd] = oacc[nd];
      l_snap = l_sum;
    }

    __builtin_amdgcn_s_setprio(1);
    if (kb != kb_d) {
      plainpass(0);
      plainpass(1);
    } else {
      // diagonal tile: lower-masked completes AR; extract AR into snap; complement
      maskpass(0, kb, false);
      maskpass(1, kb, false);
      {
        float lar_h = l_sum - l_snap;
        float lar = lar_h + __shfl_xor(lar_h, 32);
        float sAR = (1.f - a_q) / lar;
#pragma unroll
        for (int nd = 0; nd < 4; nd++)
#pragma unroll
          for (int r = 0; r < 16; r++)
            snap[nd][r] = (oacc[nd][r] - snap[nd][r]) * sAR;
      }
      maskpass(0, kb, true);
      maskpass(1, kb, true);
    }
    __builtin_amdgcn_s_setprio(0);
  }

  // combine softmax denominator across lane halves
  l_sum += __shfl_xor(l_sum, 32);
  float inv = a_q / l_sum;

  // epilogue: merged = a·O_b/l_b + (1-a)·O_ar/l_ar (all regs);
  // O^T -> LDS -> coalesced store, in two 4-wave phases (LDS capacity)
  __syncthreads();  // all waves done with lk/lvt
#pragma unroll
  for (int ph = 0; ph < 2; ph++) {
    bool act = (w >> 2) == ph;
    short* tile = sh + (w & 3) * (32 * 136);
    if (act) {
#pragma unroll
      for (int nd = 0; nd < 4; nd++)
#pragma unroll
        for (int rg = 0; rg < 4; rg++) {
          v4s pk;
#pragma unroll
          for (int i = 0; i < 4; i++) {
            float val = oacc[nd][rg * 4 + i] * inv + snap[nd][rg * 4 + i];
            pk[i] = f2bfbits(val);
          }
          // d = nd*32 + rg*8 + h8*4 + i  (C/D row formula), q = l5
          *reinterpret_cast<v4s*>(&tile[l5 * 136 + nd * 32 + rg * 8 + h8 * 4]) = pk;
        }
    }
    __syncthreads();
    if (act) {
#pragma unroll
      for (int i = 0; i < 8; i++) {
        int r = i * 4 + (lane >> 4);
        int q2 = q0 + r;
        int dcol = (lane & 15) * 8;
        v8s mv = *reinterpret_cast<const v8s*>(&tile[r * 136 + dcol]);
        size_t gbase = ((size_t)b * T_SEQ + q2) * DMODEL + h * HDIM + dcol;
        *reinterpret_cast<v8s*>((void*)(out + gbase)) = mv;
      }
    }
    __syncthreads();
  }
}

extern "C" void kernel_launch(void* const* d_in, const int* in_sizes, int n_in,
                              void* d_out, int out_size, void* d_ws, size_t ws_size,
                              hipStream_t stream) {
  const void* x_raw    = d_in[0];
  const void* unc_raw  = d_in[1];
  const void* Wqd_raw  = d_in[2];
  const void* qnw_raw  = d_in[3];
  const void* Wqu_raw  = d_in[4];
  const void* Wqr_raw  = d_in[5];
  const void* Wkvd_raw = d_in[6];
  const void* kvnw_raw = d_in[7];
  const void* Wku_raw  = d_in[8];
  const void* Wvu_raw  = d_in[9];
  const void* Wkr_raw  = d_in[10];
  const void* Wo_raw   = d_in[11];
  const void* Wg_raw   = d_in[12];
  const void* bg_raw   = d_in[13];

  char* ws = (char*)d_ws;
  size_t off = 0;
  auto alloc = [&](size_t bytes) -> void* {
    char* p = ws + off;
    off += (bytes + 255) & ~(size_t)255;
    return p;
  };
  int*  flag   = (int*)alloc(256);
  bf16* xc     = (bf16*)alloc((size_t)4096 * 2048 * 2);
  float* uncf  = (float*)alloc((size_t)4096 * 4);
  bf16* qnw    = (bf16*)alloc(1536 * 2);
  bf16* kvnw   = (bf16*)alloc(512 * 2);
  bf16* wgc    = (bf16*)alloc(2048 * 2);
  bf16* bgc    = (bf16*)alloc(256);
  bf16* BT1    = (bf16*)alloc((size_t)3072 * 2048 * 2);  // [WqdT;WkvdT;WkrT], K=2048
  bf16* BT2    = (bf16*)alloc((size_t)3072 * 1536 * 2);  // [WquT;WqrT], K=1536
  bf16* BT3    = (bf16*)alloc((size_t)4096 * 512 * 2);   // [WkuT;WvuT], K=512
  bf16* WoT    = (bf16*)alloc((size_t)2048 * 2048 * 2);
  bf16* xproj  = (bf16*)alloc((size_t)4096 * 3072 * 2);  // [q_raw|kv_raw|k_r]
  bf16* q_lat  = (bf16*)alloc((size_t)4096 * 1536 * 2);
  bf16* kv_lat = (bf16*)alloc((size_t)4096 * 512 * 2);
  bf16* qcr    = (bf16*)alloc((size_t)4096 * 3072 * 2);  // [q_c|q_r]
  bf16* kcv    = (bf16*)alloc((size_t)4096 * 4096 * 2);  // [k_c|v]
  bf16* vT     = (bf16*)alloc((size_t)4096 * 2048 * 2);
  bf16* attno  = (bf16*)alloc((size_t)4096 * 2048 * 2);  // merged attention out
  float* alphaF= (float*)alloc((size_t)4096 * 4);

  detect_k<<<1, 256, 0, stream>>>((const unsigned*)x_raw, flag);

  conv_all<<<8225, 256, 0, stream>>>(x_raw, qnw_raw, kvnw_raw, Wg_raw, bg_raw, unc_raw,
                                     xc, qnw, kvnw, wgc, bgc, uncf, flag);

  // one dispatch for all 8 weight transposes
  TP8 jobs;
  const void* srcs[8] = {Wqd_raw, Wkvd_raw, Wkr_raw, Wqu_raw, Wqr_raw, Wku_raw, Wvu_raw, Wo_raw};
  bf16* dsts[8] = {BT1, BT1 + (size_t)1536 * 2048, BT1 + (size_t)2048 * 2048,
                   BT2, BT2 + (size_t)2048 * 1536,
                   BT3, BT3 + (size_t)2048 * 512, WoT};
  int rws[8] = {2048, 2048, 2048, 1536, 1536, 512, 512, 2048};
  int cls[8] = {1536, 512, 1024, 2048, 1024, 2048, 2048, 2048};
  int acc_t = 0;
  for (int i = 0; i < 8; i++) {
    jobs.s[i] = srcs[i]; jobs.d[i] = dsts[i];
    jobs.rows[i] = rws[i]; jobs.cols[i] = cls[i];
    jobs.pre[i] = acc_t;
    acc_t += (rws[i] / 32) * (cls[i] / 32);
  }
  jobs.pre[8] = acc_t;
  transpose_all<<<acc_t, 256, 0, stream>>>(jobs, flag);

  auto gemm8b = [&](const bf16* A, const bf16* BT, bf16* C, int M, int N, int K,
                    const int* oflag, void* dvout) {
    gemm8<<<dim3(N / 256, M / 256), 512, 0, stream>>>(A, BT, C, M, N, K, oflag, dvout);
  };

  gemm8b(xc, BT1, xproj, 4096, 3072, 2048, nullptr, nullptr);   // [q_raw|kv_raw|k_r]
  rmsnorm_both<<<8192, 256, 0, stream>>>(xproj, qnw, kvnw, q_lat, kv_lat);
  gemm8b(q_lat, BT2, qcr, 4096, 3072, 1536, nullptr, nullptr);  // [q_c|q_r]
  gemm8b(kv_lat, BT3, kcv, 4096, 4096, 512, nullptr, nullptr);  // [k_c|v]

  // V^T: vT[d][b*T+t] from kcv cols 2048..4095
  transpose_str<<<dim3(64, 128), 256, 0, stream>>>(kcv + 2048, vT, 4096, 4096);

  rope_gate<<<12288, 256, 0, stream>>>(qcr, xproj, uncf, xc, wgc, bgc, alphaF, d_out, flag);

  // single fused attention (bidir + AR + alpha-merge), Q-tile 256, 8 waves,
  // XCD-pair-colocated flat grid (256 blocks = 8 qt x 32 pairs)
  attn_f<<<256, 512, 0, stream>>>(qcr, kcv, xproj, vT, alphaF, attno);

  // final projection writes d_out directly in detected dtype
  gemm8b(attno, WoT, nullptr, 4096, 2048, 2048, flag, d_out);

  (void)in_sizes; (void)n_in; (void)out_size; (void)ws_size;
}

// Round 8
// 585.746 us; speedup vs baseline: 1.3882x; 1.0353x over previous
//
#include <hip/hip_runtime.h>
#include <hip/hip_bf16.h>
#include <math.h>

typedef __hip_bfloat16 bf16;
using v8bf = __attribute__((ext_vector_type(8))) __bf16;
using v4f  = __attribute__((ext_vector_type(4))) float;
using f32x16 = __attribute__((ext_vector_type(16))) float;
using v4u = __attribute__((ext_vector_type(4))) unsigned;
using v4s = __attribute__((ext_vector_type(4))) short;
using v8s = __attribute__((ext_vector_type(8))) short;

#define T_SEQ 2048
#define DMODEL 2048
#define NHEADS 16
#define HDIM 128
#define RDIM 64

__device__ __forceinline__ short f2bfbits(float f) {
  bf16 h = __float2bfloat16(f);
  short s;
  __builtin_memcpy(&s, &h, 2);
  return s;
}

__device__ __forceinline__ unsigned pk2bf(float a, float b) {
  unsigned lo = (unsigned short)f2bfbits(a);
  unsigned hi = (unsigned short)f2bfbits(b);
  return lo | (hi << 16);
}

// async global->LDS, 16B per lane
typedef const __attribute__((address_space(1))) unsigned gu32;
typedef __attribute__((address_space(3))) unsigned lu32;
__device__ __forceinline__ void gl_lds16(const void* g, void* l) {
  __builtin_amdgcn_global_load_lds((gu32*)g, (lu32*)l, 16, 0, 0);
}

template <int N>
__device__ __forceinline__ void vwn() {
  asm volatile("s_waitcnt vmcnt(%0)" :: "n"(N) : "memory");
}

// raw barrier + compiler memory fence (no vmcnt drain, unlike __syncthreads)
__device__ __forceinline__ void barx() {
  __builtin_amdgcn_s_barrier();
  asm volatile("" ::: "memory");
}

// ---------------- dtype detection ----------------
__global__ void detect_k(const unsigned* __restrict__ x, int* __restrict__ flag) {
  __shared__ int cnt;
  if (threadIdx.x == 0) cnt = 0;
  __syncthreads();
  int c = 0;
#pragma unroll
  for (int i = 0; i < 4; i++) {
    unsigned w = x[threadIdx.x * 4 + i];
    unsigned e = (w >> 7) & 0xFFu;
    if (e < 97u || e > 157u) c++;
  }
  atomicAdd(&cnt, c);
  __syncthreads();
  if (threadIdx.x == 0) flag[0] = (cnt > 256) ? 1 : 0;  // 1 = f32 inputs
}

// ---------------- fused canonicalize: x (vectorized x4) + all small inputs ----------------
__global__ __launch_bounds__(256) void conv_all(const void* x_raw,
                                                const void* qnw_raw, const void* kvnw_raw,
                                                const void* wg_raw, const void* bg_raw,
                                                const void* unc_raw,
                                                bf16* xc, bf16* qnw, bf16* kvnw,
                                                bf16* wgc, bf16* bgc, float* uncf,
                                                const int* flag) {
  bool isf = (*flag != 0);
  if (blockIdx.x < 8192) {
    int i4 = blockIdx.x * 256 + threadIdx.x;   // vector index (4 elems each)
    v4s o;
    if (isf) {
      float4 v = ((const float4*)x_raw)[i4];
      o[0] = f2bfbits(v.x); o[1] = f2bfbits(v.y);
      o[2] = f2bfbits(v.z); o[3] = f2bfbits(v.w);
    } else {
      o = ((const v4s*)x_raw)[i4];
    }
    *reinterpret_cast<v4s*>(xc + (size_t)i4 * 4) = o;
  } else {
    int i = (blockIdx.x - 8192) * 256 + threadIdx.x;
    if (i < 1536) qnw[i] = isf ? __float2bfloat16(((const float*)qnw_raw)[i]) : ((const bf16*)qnw_raw)[i];
    else if (i < 2048) { int j = i - 1536; kvnw[j] = isf ? __float2bfloat16(((const float*)kvnw_raw)[j]) : ((const bf16*)kvnw_raw)[j]; }
    else if (i < 4096) { int j = i - 2048; wgc[j] = isf ? __float2bfloat16(((const float*)wg_raw)[j]) : ((const bf16*)wg_raw)[j]; }
    else if (i < 4097) bgc[0] = isf ? __float2bfloat16(((const float*)bg_raw)[0]) : ((const bf16*)bg_raw)[0];
    else if (i < 8193) { int j = i - 4097; uncf[j] = isf ? ((const float*)unc_raw)[j] : __bfloat162float(((const bf16*)unc_raw)[j]); }
  }
}

// ---------------- all 8 weight transposes in one dispatch ----------------
struct TP8 {
  const void* s[8];
  bf16* d[8];
  int rows[8];
  int cols[8];
  int pre[9];
};

__global__ __launch_bounds__(256) void transpose_all(TP8 jobs, const int* __restrict__ flag) {
  __shared__ bf16 tile[32][33];
  int bid = blockIdx.x;
  int w = 0;
#pragma unroll
  for (int k = 0; k < 7; k++) if (bid >= jobs.pre[k + 1]) w = k + 1;
  int lt = bid - jobs.pre[w];
  int rows = jobs.rows[w], cols = jobs.cols[w];
  int tpr = cols >> 5;
  int by = (lt / tpr) << 5, bx = (lt % tpr) << 5;
  const void* src = jobs.s[w];
  bf16* dst = jobs.d[w];
  int tx = threadIdx.x & 31, ty = threadIdx.x >> 5;
  bool isf = (*flag != 0);
#pragma unroll
  for (int i = 0; i < 32; i += 8) {
    size_t idx = (size_t)(by + ty + i) * cols + bx + tx;
    tile[ty + i][tx] = isf ? __float2bfloat16(((const float*)src)[idx])
                           : ((const bf16*)src)[idx];
  }
  __syncthreads();
#pragma unroll
  for (int i = 0; i < 32; i += 8)
    dst[(size_t)(bx + ty + i) * rows + by + tx] = tile[tx][ty + i];
}

// ---------------- strided bf16 transpose (V^T out of fused kcv) ----------------
__global__ __launch_bounds__(256) void transpose_str(const bf16* __restrict__ src,
                                                     bf16* __restrict__ dst,
                                                     int srcStride, int dstStride) {
  __shared__ bf16 tile[32][33];
  int bx = blockIdx.x * 32, by = blockIdx.y * 32;
  int tx = threadIdx.x & 31, ty = threadIdx.x >> 5;
#pragma unroll
  for (int i = 0; i < 32; i += 8)
    tile[ty + i][tx] = src[(size_t)(by + ty + i) * srcStride + bx + tx];
  __syncthreads();
#pragma unroll
  for (int i = 0; i < 32; i += 8)
    dst[(size_t)(bx + ty + i) * dstStride + by + tx] = tile[tx][ty + i];
}

// ---------------- 8-phase 256x256 TN GEMM, snake-quadrant schedule ----------------
// 512 thr / 8 waves, BK=64, LDS 128 KiB dbuf. Per K-tile 4 phases in SNAKE order
// (0,0)->(0,1)->(1,1)->(1,0): consecutive phases share an operand half ->
// reads/phase = 12/8/4/8 b128 per 16 MFMA/wave (ratio 2.0). Swizzle
// byte ^= (row&7)<<4 on BOTH gl_lds source and ds_read (2-way = free, attn-proven).
// One half-tile staged per phase AFTER the barrier (WAR-safe); counted vmcnt(4)
// at 3 of 4 phases, never 0 in steady state; raw s_barrier (no ds_writes in loop).
__global__ __launch_bounds__(512, 2) void gemm8(const bf16* __restrict__ A,
                                                const bf16* __restrict__ BT,
                                                bf16* __restrict__ Cb,
                                                int M, int N, int K,
                                                const int* __restrict__ oflag,
                                                void* __restrict__ dvout) {
  __shared__ __align__(16) short lds[2][2][16384];  // [buf][0=A,1=B][256*64]
  const int m0 = blockIdx.y * 256, n0 = blockIdx.x * 256;
  const int tid = threadIdx.x;
  const int w = tid >> 6, lane = tid & 63;
  const int quad4 = lane >> 4, l16 = lane & 15;
  const int wmq = (w >> 1) * 32;   // 4 M-groups of 32 rows
  const int wnq = (w & 1) * 64;    // 2 N-groups of 64 cols

  v4f acc[4][2][4];
#pragma unroll
  for (int qi = 0; qi < 4; qi++)
#pragma unroll
    for (int mf = 0; mf < 2; mf++)
#pragma unroll
      for (int nf = 0; nf < 4; nf++) acc[qi][mf][nf] = (v4f){0.f, 0.f, 0.f, 0.f};

  // stage one half-tile (sp: 0=A0,1=B0,2=B1,3=A1) of K-tile kb into buf sbuf
  auto stage_half = [&](int sp, int kb, int sbuf) {
    const int mat = (sp == 0 || sp == 3) ? 0 : 1;
    const int half = (sp >= 2) ? 1 : 0;
    const bf16* base = mat ? BT : A;
    const int rb = (mat ? n0 : m0) + half * 128 + w * 16;
    const int cb = (((lane & 7) ^ (lane >> 3)) << 4);  // pre-swizzled col byte
#pragma unroll
    for (int i = 0; i < 2; i++) {
      short* dst = &lds[sbuf][mat][(half * 128 + w * 16 + i * 8) * 64];
      int grow = rb + i * 8 + (lane >> 3);
      const bf16* src = base + (size_t)grow * K + kb + (cb >> 1);
      gl_lds16(src, dst);
    }
  };

  v8bf a_[2][2], b_[2][4];
  auto loadA = [&](int bufb, int qm) {
#pragma unroll
    for (int ks = 0; ks < 2; ks++)
#pragma unroll
      for (int mf = 0; mf < 2; mf++) {
        int r_ = qm * 128 + wmq + mf * 16 + l16;
        int c_ = (ks * 64 + quad4 * 16) ^ ((r_ & 7) << 4);
        a_[ks][mf] = *reinterpret_cast<const v8bf*>(
            (const char*)&lds[bufb][0][0] + r_ * 128 + c_);
      }
  };
  auto loadB = [&](int bufb, int qn) {
#pragma unroll
    for (int ks = 0; ks < 2; ks++)
#pragma unroll
      for (int nf = 0; nf < 4; nf++) {
        int r_ = qn * 128 + wnq + nf * 16 + l16;
        int c_ = (ks * 64 + quad4 * 16) ^ ((r_ & 7) << 4);
        b_[ks][nf] = *reinterpret_cast<const v8bf*>(
            (const char*)&lds[bufb][1][0] + r_ * 128 + c_);
      }
  };

#define MMQ(QI) do {                                                              \
    __builtin_amdgcn_s_setprio(1);                                                \
    _Pragma("unroll")                                                             \
    for (int ks = 0; ks < 2; ks++)                                                \
      _Pragma("unroll")                                                           \
      for (int mf = 0; mf < 2; mf++)                                              \
        _Pragma("unroll")                                                         \
        for (int nf = 0; nf < 4; nf++)                                            \
          acc[QI][mf][nf] = __builtin_amdgcn_mfma_f32_16x16x32_bf16(              \
              a_[ks][mf], b_[ks][nf], acc[QI][mf][nf], 0, 0, 0);                  \
    __builtin_amdgcn_s_setprio(0);                                                \
  } while (0)

  const int T = K >> 6;  // K % 64 == 0, T >= 2

  // prologue: stage tile0 (8 loads/thread outstanding)
#pragma unroll
  for (int sp = 0; sp < 4; sp++) stage_half(sp, 0, 0);

  for (int t = 0; t < T - 1; t++) {
    const int buf = t & 1, sb = buf ^ 1, kbn = (t + 1) << 6;
    // p00: need A0,B0 (oldest 4 of 8)
    vwn<4>(); barx(); stage_half(0, kbn, sb); loadA(buf, 0); loadB(buf, 0); MMQ(0);
    // p01: need B1 (oldest 2 of 6)
    vwn<4>(); barx(); stage_half(1, kbn, sb); loadB(buf, 1); MMQ(1);
    // p11: need A1 (oldest 2 of 6)
    vwn<4>(); barx(); stage_half(2, kbn, sb); loadA(buf, 1); MMQ(3);
    // p10: B0 already drained
    barx(); stage_half(3, kbn, sb); loadB(buf, 0); MMQ(2);
  }
  {  // last tile: no staging; drain progressively
    const int buf = (T - 1) & 1;
    vwn<4>(); barx(); loadA(buf, 0); loadB(buf, 0); MMQ(0);
    vwn<2>(); barx(); loadB(buf, 1); MMQ(1);
    vwn<0>(); barx(); loadA(buf, 1); MMQ(3);
    barx(); loadB(buf, 0); MMQ(2);
  }
#undef MMQ

  // epilogue: C write (C/D layout: col=lane&15, row=(lane>>4)*4+r)
  const bool isf = dvout && (*oflag != 0);
#pragma unroll
  for (int qi = 0; qi < 4; qi++) {
    const int qm = qi >> 1, qn = qi & 1;
#pragma unroll
    for (int mf = 0; mf < 2; mf++)
#pragma unroll
      for (int nf = 0; nf < 4; nf++)
#pragma unroll
        for (int r = 0; r < 4; r++) {
          int row = m0 + qm * 128 + wmq + mf * 16 + quad4 * 4 + r;
          int col = n0 + qn * 128 + wnq + nf * 16 + l16;
          float vv = acc[qi][mf][nf][r];
          size_t idx = (size_t)row * N + col;
          if (dvout) {
            if (isf) ((float*)dvout)[idx] = vv;
            else     ((bf16*)dvout)[idx] = __float2bfloat16(vv);
          } else {
            Cb[idx] = __float2bfloat16(vv);
          }
        }
  }
}

// ---------------- both RMS norms in one dispatch ----------------
__global__ __launch_bounds__(256) void rmsnorm_both(const bf16* __restrict__ xproj,
                                                    const bf16* __restrict__ qnw,
                                                    const bf16* __restrict__ kvnw,
                                                    bf16* __restrict__ q_lat,
                                                    bf16* __restrict__ kv_lat) {
  int bid = blockIdx.x, tid = threadIdx.x;
  bool isq = bid < 4096;
  int row = isq ? bid : bid - 4096;
  int C = isq ? 1536 : 512;
  const bf16* r = xproj + (size_t)row * 3072 + (isq ? 0 : 1536);
  const bf16* w = isq ? qnw : kvnw;
  bf16* o = (isq ? q_lat : kv_lat) + (size_t)row * C;
  float s = 0.f;
  for (int i = tid; i < C; i += 256) { float v = __bfloat162float(r[i]); s += v * v; }
#pragma unroll
  for (int m = 32; m; m >>= 1) s += __shfl_xor(s, m);
  __shared__ float red[4];
  if ((tid & 63) == 0) red[tid >> 6] = s;
  __syncthreads();
  float tot = red[0] + red[1] + red[2] + red[3];
  float rs = rsqrtf(tot / (float)C + 1e-6f);
  for (int i = tid; i < C; i += 256)
    o[i] = __float2bfloat16(__bfloat162float(r[i]) * rs * __bfloat162float(w[i]));
}

// ---------------- rope (q_r in qcr, k_r in xproj) + gate (writes d_out alpha) ----------------
__global__ __launch_bounds__(256) void rope_gate(bf16* __restrict__ qcr,
                                                 bf16* __restrict__ xproj,
                                                 const float* __restrict__ unc,
                                                 const bf16* __restrict__ x,
                                                 const bf16* __restrict__ wg,
                                                 const bf16* __restrict__ bg,
                                                 float* __restrict__ af,
                                                 void* __restrict__ dout,
                                                 const int* __restrict__ flag) {
  __shared__ float red[4];
  int tid = threadIdx.x;
  if (blockIdx.x < 8192) {
    int idx = blockIdx.x * 256 + tid;
    int j = idx & 31, h = (idx >> 5) & 15, bt = idx >> 9;
    int t = bt & (T_SEQ - 1);
    float u = unc[bt];
    u = fminf(fmaxf(u, 0.f), 1.f);
    float scale = 0.5f + 1.5f * u;
    float theta = expf(-(float)j * (1.f / 32.f) * logf(500000.f));
    float f = (float)t * theta * scale;
    float c = cosf(f), s = sinf(f);
    size_t base = (size_t)bt * 3072 + 2048 + h * RDIM + j;
    {
      float x1 = __bfloat162float(qcr[base]), x2 = __bfloat162float(qcr[base + 32]);
      qcr[base]      = __float2bfloat16(x1 * c - x2 * s);
      qcr[base + 32] = __float2bfloat16(x2 * c + x1 * s);
    }
    {
      float x1 = __bfloat162float(xproj[base]), x2 = __bfloat162float(xproj[base + 32]);
      xproj[base]      = __float2bfloat16(x1 * c - x2 * s);
      xproj[base + 32] = __float2bfloat16(x2 * c + x1 * s);
    }
  } else {
    int row = blockIdx.x - 8192;
    const bf16* xr = x + (size_t)row * DMODEL;
    float s = 0.f;
    for (int i = tid; i < DMODEL; i += 256)
      s += __bfloat162float(xr[i]) * __bfloat162float(wg[i]);
#pragma unroll
    for (int m = 32; m; m >>= 1) s += __shfl_xor(s, m);
    if ((tid & 63) == 0) red[tid >> 6] = s;
    __syncthreads();
    if (tid == 0) {
      float tot = red[0] + red[1] + red[2] + red[3] + __bfloat162float(bg[0]);
      float a = 1.f / (1.f + expf(-tot));
      af[row] = a;
      size_t oi = (size_t)8388608 + row;   // alpha region of d_out
      if (*flag) ((float*)dout)[oi] = a;
      else       ((bf16*)dout)[oi] = __float2bfloat16(a);
    }
  }
}

// ---------------- fused flash attention: bidir + windowed-causal AR, one pass ----------------
// (round-6 structure; round-8 tweaks: issue() moved AFTER the 2nd barrier so
//  loads span the compute phase instead of being drained by __syncthreads'
//  vmcnt(0); QK accumulation split into two 6-deep chains.)
__global__ __launch_bounds__(512, 2) void attn_f(const bf16* __restrict__ qcr,
                                                 const bf16* __restrict__ kcv,
                                                 const bf16* __restrict__ xproj,
                                                 const bf16* __restrict__ vt,
                                                 const float* __restrict__ alphaF,
                                                 bf16* __restrict__ out) {
  constexpr int LDK = 200;  // 192 + pad
  constexpr int LDV = 72;   // 64 + pad
  __shared__ __align__(16) short sh[64 * LDK + 128 * LDV];  // 44032 B
  short* lk  = sh;
  short* lvt = sh + 64 * LDK;

  // XCD-pair-colocating decode (HW: XCD = flat % 8): pair p -> xcd p&7
  const int f_ = blockIdx.x;
  const int xcd = f_ & 7, g_ = f_ >> 3;
  const int qt = g_ & 7;
  const int p_ = xcd + 8 * (g_ >> 3);
  const int h = p_ & 15, b = p_ >> 4;

  const int qs = qt * 256;
  const int tid = threadIdx.x;
  const int w = tid >> 6, lane = tid & 63;
  const int l5 = lane & 31, h8 = lane >> 5;
  const int q0 = qs + w * 32;
  const int myq = q0 + l5;   // this lane's q row (S^T column)

  // Q fragments (B-operand: col=lane&31, k=(lane>>5)*8+v)
  v8bf qf[12];
  {
    const bf16* qcb = qcr + ((size_t)b * T_SEQ + myq) * 3072 + h * HDIM;
#pragma unroll
    for (int ks = 0; ks < 8; ks++)
      qf[ks] = *reinterpret_cast<const v8bf*>(qcb + ks * 16 + h8 * 8);
    const bf16* qrb = qcr + ((size_t)b * T_SEQ + myq) * 3072 + 2048 + h * RDIM;
#pragma unroll
    for (int ks = 0; ks < 4; ks++)
      qf[8 + ks] = *reinterpret_cast<const v8bf*>(qrb + ks * 16 + h8 * 8);
  }

  float l_sum = 0.f, l_snap = 0.f;
  f32x16 oacc[4], snap[4];
#pragma unroll
  for (int nd = 0; nd < 4; nd++)
#pragma unroll
    for (int r = 0; r < 16; r++) { oacc[nd][r] = 0.f; snap[nd][r] = 0.f; }

  const float a_q = alphaF[b * T_SEQ + myq];
  const float sc = 0.07216878364870323f;  // 1/sqrt(192)

  // AR window: this block IS one 256-chunk (CHUNK=256). klo 64-aligned.
  const int klo  = (qt > 0) ? (qs - 256) : 0;
  const int kb_d = qs + (w >> 1) * 64;    // wave's diagonal tile

  // staging (512 threads): K_c 1024 chunks (2/thd), k_r 512 (1/thd), V^T 1024 (2/thd)
  const int koc0 = (tid >> 4) * 4096 + (tid & 15) * 8;
  const int ldc0 = (tid >> 4) * LDK  + (tid & 15) * 8;
  const int kor0 = (tid >> 3) * 3072 + (tid & 7) * 8;
  const int ldr0 = (tid >> 3) * LDK + 128 + (tid & 7) * 8;
  const int kov0 = (tid >> 3) * 4096 + (tid & 7) * 8;
  const int ldv0 = (tid >> 3) * LDV  + (tid & 7) * 8;
  const bf16* kc_base = kcv   + (size_t)b * T_SEQ * 4096 + h * HDIM;
  const bf16* kr_base = xproj + (size_t)b * T_SEQ * 3072 + 2048 + h * RDIM;
  const bf16* v_base  = vt    + (size_t)h * HDIM * (2 * T_SEQ) + b * T_SEQ;

  v4u rc[2], rr1, rv[2];
  auto issue = [&](int kb) {
    const bf16* pc = kc_base + (size_t)kb * 4096;
    const bf16* pr = kr_base + (size_t)kb * 3072;
    const bf16* pv = v_base + kb;
#pragma unroll
    for (int i = 0; i < 2; i++) rc[i] = *reinterpret_cast<const v4u*>(pc + koc0 + i * 131072);
    rr1 = *reinterpret_cast<const v4u*>(pr + kor0);
#pragma unroll
    for (int i = 0; i < 2; i++) rv[i] = *reinterpret_cast<const v4u*>(pv + kov0 + i * 262144);
  };

  auto qk = [&](int j) -> f32x16 {
    f32x16 s0, s1;
#pragma unroll
    for (int r = 0; r < 16; r++) { s0[r] = 0.f; s1[r] = 0.f; }
#pragma unroll
    for (int ks = 0; ks < 6; ks++) {
      v8bf kf0 = *reinterpret_cast<const v8bf*>(&lk[(j * 32 + l5) * LDK + (2 * ks) * 16 + h8 * 8]);
      v8bf kf1 = *reinterpret_cast<const v8bf*>(&lk[(j * 32 + l5) * LDK + (2 * ks + 1) * 16 + h8 * 8]);
      s0 = __builtin_amdgcn_mfma_f32_32x32x16_bf16(kf0, qf[2 * ks], s0, 0, 0, 0);
      s1 = __builtin_amdgcn_mfma_f32_32x32x16_bf16(kf1, qf[2 * ks + 1], s1, 0, 0, 0);
    }
#pragma unroll
    for (int r = 0; r < 16; r++) s0[r] += s1[r];
    return s0;
  };
  auto pack8 = [&](const float* p) -> v8bf {
    unsigned Y0 = pk2bf(p[0], p[1]);
    unsigned Y1 = pk2bf(p[2], p[3]);
    unsigned Y2 = pk2bf(p[4], p[5]);
    unsigned Y3 = pk2bf(p[6], p[7]);
    asm volatile("v_permlane32_swap_b32 %0, %1" : "+v"(Y0), "+v"(Y2));
    asm volatile("v_permlane32_swap_b32 %0, %1" : "+v"(Y1), "+v"(Y3));
    v4u t; t.x = Y0; t.y = Y1; t.z = Y2; t.w = Y3;
    return __builtin_bit_cast(v8bf, t);
  };
  auto pvj = [&](int j, const v8bf* pf) {
#pragma unroll
    for (int ck = 0; ck < 2; ck++)
#pragma unroll
      for (int nd = 0; nd < 4; nd++) {
        v8bf vf = *reinterpret_cast<const v8bf*>(&lvt[(nd * 32 + l5) * LDV + (j * 2 + ck) * 16 + h8 * 8]);
        oacc[nd] = __builtin_amdgcn_mfma_f32_32x32x16_bf16(vf, pf[ck], oacc[nd], 0, 0, 0);
      }
  };
  auto plainpass = [&](int j) {
    f32x16 s = qk(j);
    v8bf pf[2];
#pragma unroll
    for (int cc = 0; cc < 2; cc++) {
      float p[8];
#pragma unroll
      for (int r8 = 0; r8 < 8; r8++) {
        float e = __expf(s[cc * 8 + r8] * sc);
        p[r8] = e;
        l_sum += e;
      }
      pf[cc] = pack8(p);
    }
    pvj(j, pf);
  };
  auto maskpass = [&](int j, int kb, bool upper) {
    f32x16 s = qk(j);
    v8bf pf[2];
#pragma unroll
    for (int cc = 0; cc < 2; cc++) {
      float p[8];
#pragma unroll
      for (int r8 = 0; r8 < 8; r8++) {
        int r = cc * 8 + r8;
        int kk = kb + j * 32 + (r & 3) + 8 * (r >> 2) + 4 * h8;
        float e = __expf(s[r] * sc);
        bool keep = upper ? (kk > myq) : (kk <= myq);
        e = keep ? e : 0.f;
        p[r8] = e;
        l_sum += e;
      }
      pf[cc] = pack8(p);
    }
    pvj(j, pf);
  };

  issue(0);

  for (int kb = 0; kb < T_SEQ; kb += 64) {
    __syncthreads();  // WAR: all waves done reading previous tile
    // commit prefetched tile to LDS (loads were issued one full iter ago)
#pragma unroll
    for (int i = 0; i < 2; i++) *reinterpret_cast<v4u*>(&lk[ldc0 + i * 32 * LDK]) = rc[i];
    *reinterpret_cast<v4u*>(&lk[ldr0]) = rr1;
#pragma unroll
    for (int i = 0; i < 2; i++) *reinterpret_cast<v4u*>(&lvt[ldv0 + i * 64 * LDV]) = rv[i];
    __syncthreads();
    // issue next tile AFTER the barrier: loads stay in flight through compute
    if (kb + 64 < T_SEQ) issue(kb + 64);

    if (kb == klo) {  // snapshot pre-window state (wave-uniform branch)
#pragma unroll
      for (int nd = 0; nd < 4; nd++) snap[nd] = oacc[nd];
      l_snap = l_sum;
    }

    __builtin_amdgcn_s_setprio(1);
    if (kb != kb_d) {
      plainpass(0);
      plainpass(1);
    } else {
      // diagonal tile: lower-masked completes AR; extract AR into snap; complement
      maskpass(0, kb, false);
      maskpass(1, kb, false);
      {
        float lar_h = l_sum - l_snap;
        float lar = lar_h + __shfl_xor(lar_h, 32);
        float sAR = (1.f - a_q) / lar;
#pragma unroll
        for (int nd = 0; nd < 4; nd++)
#pragma unroll
          for (int r = 0; r < 16; r++)
            snap[nd][r] = (oacc[nd][r] - snap[nd][r]) * sAR;
      }
      maskpass(0, kb, true);
      maskpass(1, kb, true);
    }
    __builtin_amdgcn_s_setprio(0);
  }

  // combine softmax denominator across lane halves
  l_sum += __shfl_xor(l_sum, 32);
  float inv = a_q / l_sum;

  // epilogue: merged = a·O_b/l_b + (1-a)·O_ar/l_ar (all regs);
  // O^T -> LDS -> coalesced store, in two 4-wave phases (LDS capacity)
  __syncthreads();  // all waves done with lk/lvt
#pragma unroll
  for (int ph = 0; ph < 2; ph++) {
    bool act = (w >> 2) == ph;
    short* tile = sh + (w & 3) * (32 * 136);
    if (act) {
#pragma unroll
      for (int nd = 0; nd < 4; nd++)
#pragma unroll
        for (int rg = 0; rg < 4; rg++) {
          v4s pk;
#pragma unroll
          for (int i = 0; i < 4; i++) {
            float val = oacc[nd][rg * 4 + i] * inv + snap[nd][rg * 4 + i];
            pk[i] = f2bfbits(val);
          }
          // d = nd*32 + rg*8 + h8*4 + i  (C/D row formula), q = l5
          *reinterpret_cast<v4s*>(&tile[l5 * 136 + nd * 32 + rg * 8 + h8 * 4]) = pk;
        }
    }
    __syncthreads();
    if (act) {
#pragma unroll
      for (int i = 0; i < 8; i++) {
        int r = i * 4 + (lane >> 4);
        int q2 = q0 + r;
        int dcol = (lane & 15) * 8;
        v8s mv = *reinterpret_cast<const v8s*>(&tile[r * 136 + dcol]);
        size_t gbase = ((size_t)b * T_SEQ + q2) * DMODEL + h * HDIM + dcol;
        *reinterpret_cast<v8s*>((void*)(out + gbase)) = mv;
      }
    }
    __syncthreads();
  }
}

extern "C" void kernel_launch(void* const* d_in, const int* in_sizes, int n_in,
                              void* d_out, int out_size, void* d_ws, size_t ws_size,
                              hipStream_t stream) {
  const void* x_raw    = d_in[0];
  const void* unc_raw  = d_in[1];
  const void* Wqd_raw  = d_in[2];
  const void* qnw_raw  = d_in[3];
  const void* Wqu_raw  = d_in[4];
  const void* Wqr_raw  = d_in[5];
  const void* Wkvd_raw = d_in[6];
  const void* kvnw_raw = d_in[7];
  const void* Wku_raw  = d_in[8];
  const void* Wvu_raw  = d_in[9];
  const void* Wkr_raw  = d_in[10];
  const void* Wo_raw   = d_in[11];
  const void* Wg_raw   = d_in[12];
  const void* bg_raw   = d_in[13];

  char* ws = (char*)d_ws;
  size_t off = 0;
  auto alloc = [&](size_t bytes) -> void* {
    char* p = ws + off;
    off += (bytes + 255) & ~(size_t)255;
    return p;
  };
  int*  flag   = (int*)alloc(256);
  bf16* xc     = (bf16*)alloc((size_t)4096 * 2048 * 2);
  float* uncf  = (float*)alloc((size_t)4096 * 4);
  bf16* qnw    = (bf16*)alloc(1536 * 2);
  bf16* kvnw   = (bf16*)alloc(512 * 2);
  bf16* wgc    = (bf16*)alloc(2048 * 2);
  bf16* bgc    = (bf16*)alloc(256);
  bf16* BT1    = (bf16*)alloc((size_t)3072 * 2048 * 2);  // [WqdT;WkvdT;WkrT], K=2048
  bf16* BT2    = (bf16*)alloc((size_t)3072 * 1536 * 2);  // [WquT;WqrT], K=1536
  bf16* BT3    = (bf16*)alloc((size_t)4096 * 512 * 2);   // [WkuT;WvuT], K=512
  bf16* WoT    = (bf16*)alloc((size_t)2048 * 2048 * 2);
  bf16* xproj  = (bf16*)alloc((size_t)4096 * 3072 * 2);  // [q_raw|kv_raw|k_r]
  bf16* q_lat  = (bf16*)alloc((size_t)4096 * 1536 * 2);
  bf16* kv_lat = (bf16*)alloc((size_t)4096 * 512 * 2);
  bf16* qcr    = (bf16*)alloc((size_t)4096 * 3072 * 2);  // [q_c|q_r]
  bf16* kcv    = (bf16*)alloc((size_t)4096 * 4096 * 2);  // [k_c|v]
  bf16* vT     = (bf16*)alloc((size_t)4096 * 2048 * 2);
  bf16* attno  = (bf16*)alloc((size_t)4096 * 2048 * 2);  // merged attention out
  float* alphaF= (float*)alloc((size_t)4096 * 4);

  detect_k<<<1, 256, 0, stream>>>((const unsigned*)x_raw, flag);

  conv_all<<<8225, 256, 0, stream>>>(x_raw, qnw_raw, kvnw_raw, Wg_raw, bg_raw, unc_raw,
                                     xc, qnw, kvnw, wgc, bgc, uncf, flag);

  // one dispatch for all 8 weight transposes
  TP8 jobs;
  const void* srcs[8] = {Wqd_raw, Wkvd_raw, Wkr_raw, Wqu_raw, Wqr_raw, Wku_raw, Wvu_raw, Wo_raw};
  bf16* dsts[8] = {BT1, BT1 + (size_t)1536 * 2048, BT1 + (size_t)2048 * 2048,
                   BT2, BT2 + (size_t)2048 * 1536,
                   BT3, BT3 + (size_t)2048 * 512, WoT};
  int rws[8] = {2048, 2048, 2048, 1536, 1536, 512, 512, 2048};
  int cls[8] = {1536, 512, 1024, 2048, 1024, 2048, 2048, 2048};
  int acc_t = 0;
  for (int i = 0; i < 8; i++) {
    jobs.s[i] = srcs[i]; jobs.d[i] = dsts[i];
    jobs.rows[i] = rws[i]; jobs.cols[i] = cls[i];
    jobs.pre[i] = acc_t;
    acc_t += (rws[i] / 32) * (cls[i] / 32);
  }
  jobs.pre[8] = acc_t;
  transpose_all<<<acc_t, 256, 0, stream>>>(jobs, flag);

  auto gemm8b = [&](const bf16* A, const bf16* BT, bf16* C, int M, int N, int K,
                    const int* oflag, void* dvout) {
    gemm8<<<dim3(N / 256, M / 256), 512, 0, stream>>>(A, BT, C, M, N, K, oflag, dvout);
  };

  gemm8b(xc, BT1, xproj, 4096, 3072, 2048, nullptr, nullptr);   // [q_raw|kv_raw|k_r]
  rmsnorm_both<<<8192, 256, 0, stream>>>(xproj, qnw, kvnw, q_lat, kv_lat);
  gemm8b(q_lat, BT2, qcr, 4096, 3072, 1536, nullptr, nullptr);  // [q_c|q_r]
  gemm8b(kv_lat, BT3, kcv, 4096, 4096, 512, nullptr, nullptr);  // [k_c|v]

  // V^T: vT[d][b*T+t] from kcv cols 2048..4095
  transpose_str<<<dim3(64, 128), 256, 0, stream>>>(kcv + 2048, vT, 4096, 4096);

  rope_gate<<<12288, 256, 0, stream>>>(qcr, xproj, uncf, xc, wgc, bgc, alphaF, d_out, flag);

  // single fused attention (bidir + AR + alpha-merge), Q-tile 256, 8 waves,
  // XCD-pair-colocated flat grid (256 blocks = 8 qt x 32 pairs)
  attn_f<<<256, 512, 0, stream>>>(qcr, kcv, xproj, vT, alphaF, attno);

  // final projection writes d_out directly in detected dtype
  gemm8b(attno, WoT, nullptr, 4096, 2048, 2048, flag, d_out);

  (void)in_sizes; (void)n_in; (void)out_size; (void)ws_size;
}